// Round 1
// baseline (28509.222 us; speedup 1.0000x reference)
//
#include <hip/hip_runtime.h>
#include <cstdint>
#include <cstddef>

#define DEVI __device__ __forceinline__

static constexpr int B_ = 4, AT = 48, NBRS = 20;
static constexpr int R2 = B_ * AT * NBRS;   // 3840 (b,i,j) rows
static constexpr int M4 = R2 * NBRS;        // 76800 (b,i,j,k) rows

// ---------------- workspace layout (in floats) ----------------
static constexpr size_t SZ_WN2A = (size_t)8 * 512 * 128;
static constexpr size_t SZ_WN2B = (size_t)8 * 128 * 512;
static constexpr size_t SZ_WN3A = (size_t)8 * 640 * 320;
static constexpr size_t SZ_WN3B = (size_t)8 * 128 * 640;
static constexpr size_t OFF_WN2A = 0;
static constexpr size_t OFF_WN2B = OFF_WN2A + SZ_WN2A;
static constexpr size_t OFF_WN3A = OFF_WN2B + SZ_WN2B;
static constexpr size_t OFF_WN3B = OFF_WN3A + SZ_WN3A;
static constexpr size_t OFF_RS2A = OFF_WN3B + SZ_WN3B;  // 512
static constexpr size_t OFF_RS2B = OFF_RS2A + 512;      // 128
static constexpr size_t OFF_RS3A = OFF_RS2B + 128;      // 640
static constexpr size_t OFF_RS3B = OFF_RS3A + 640;      // 128
static constexpr size_t OFF_SLOT = OFF_RS3B + 128;      // 8 u32 (4 min/max pairs)
static constexpr size_t OFF_BN   = OFF_SLOT + 8;        // 256: m2,v2,m3,v3
static constexpr size_t OFF_C2IN = OFF_BN + 256;        // 3840*128
static constexpr size_t OFF_Z1   = OFF_C2IN + (size_t)R2 * 128;  // 3840*512
static constexpr size_t OFF_C2B  = OFF_Z1 + (size_t)R2 * 512;    // 3840*512
static constexpr size_t OFF_Z2   = OFF_C2B + (size_t)R2 * 512;   // 3840*128
static constexpr size_t OFF_TWO  = OFF_Z2 + (size_t)R2 * 128;    // 3840*64
static constexpr size_t OFF_NK   = OFF_TWO + (size_t)R2 * 64;    // 3840*64
static constexpr size_t OFF_P1   = OFF_NK + (size_t)R2 * 64;     // 192*640
static constexpr size_t OFF_P2   = OFF_P1 + (size_t)192 * 640;   // 3840*640
static constexpr size_t OFF_P3   = OFF_P2 + (size_t)R2 * 640;    // 3840*640
static constexpr size_t OFF_TSUM = OFF_P3 + (size_t)R2 * 640;    // 3840*64

// ---------------- threefry-2x32 (JAX-compatible) ----------------
DEVI void tf2x32(unsigned k0, unsigned k1, unsigned x0, unsigned x1,
                 unsigned& o0, unsigned& o1) {
  unsigned ks0 = k0, ks1 = k1, ks2 = k0 ^ k1 ^ 0x1BD11BDAu;
  x0 += ks0; x1 += ks1;
  const unsigned rotA[4] = {13u, 15u, 26u, 6u};
  const unsigned rotB[4] = {17u, 29u, 16u, 24u};
  unsigned ks[3] = {ks0, ks1, ks2};
  #pragma unroll
  for (int i = 0; i < 5; ++i) {
    const unsigned* rot = (i & 1) ? rotB : rotA;
    #pragma unroll
    for (int r = 0; r < 4; ++r) {
      x0 += x1;
      x1 = (x1 << rot[r]) | (x1 >> (32u - rot[r]));
      x1 ^= x0;
    }
    x0 += ks[(i + 1) % 3];
    x1 += ks[(i + 2) % 3] + (unsigned)(i + 1);
  }
  o0 = x0; o1 = x1;
}

// XLA ErfInv (f32, Giles polynomial)
DEVI float erfinv_xla(float x) {
  float w = -log1pf(-x * x);
  float p;
  if (w < 5.f) {
    w -= 2.5f;
    p = 2.81022636e-08f;
    p = fmaf(p, w, 3.43273939e-07f);
    p = fmaf(p, w, -3.5233877e-06f);
    p = fmaf(p, w, -4.39150654e-06f);
    p = fmaf(p, w, 0.00021858087f);
    p = fmaf(p, w, -0.00125372503f);
    p = fmaf(p, w, -0.00417768164f);
    p = fmaf(p, w, 0.246640727f);
    p = fmaf(p, w, 1.50140941f);
  } else {
    w = sqrtf(w) - 3.f;
    p = -0.000200214257f;
    p = fmaf(p, w, 0.000100950558f);
    p = fmaf(p, w, 0.00134934322f);
    p = fmaf(p, w, -0.00367342844f);
    p = fmaf(p, w, 0.00573950773f);
    p = fmaf(p, w, -0.0076224613f);
    p = fmaf(p, w, 0.00943887047f);
    p = fmaf(p, w, 1.00167406f);
    p = fmaf(p, w, 2.83297682f);
  }
  return p * x;
}

DEVI float normal_from_bits(unsigned bits) {
  unsigned fb = (bits >> 9) | 0x3F800000u;
  float f = __uint_as_float(fb) - 1.0f;          // [0,1)
  const float lo = -0.99999994f;                 // nextafter(-1,0)
  float u = f * (1.0f - lo) + lo;
  u = fmaxf(lo, u);
  return 1.41421356237f * erfinv_xla(u);
}

// ordered-uint encoding for float atomic min/max
DEVI unsigned f2o(float f) { unsigned u = __float_as_uint(f); return (u & 0x80000000u) ? ~u : (u | 0x80000000u); }
DEVI float o2f(unsigned u) { return (u & 0x80000000u) ? __uint_as_float(u & 0x7FFFFFFFu) : __uint_as_float(~u); }

DEVI void blockMinMax(float lmn, float lmx, float* smem, unsigned* slot) {
  float* smn = smem; float* smx = smem + 256;
  int t = threadIdx.x;
  smn[t] = lmn; smx[t] = lmx;
  __syncthreads();
  for (int s = 128; s > 0; s >>= 1) {
    if (t < s) { smn[t] = fminf(smn[t], smn[t + s]); smx[t] = fmaxf(smx[t], smx[t + s]); }
    __syncthreads();
  }
  if (t == 0) { atomicMin(slot + 0, f2o(smn[0])); atomicMax(slot + 1, f2o(smx[0])); }
}

// ---------------- kernels ----------------
__global__ __launch_bounds__(256) void k_init(float* __restrict__ tsum, unsigned* __restrict__ slots) {
  int i = blockIdx.x * 256 + threadIdx.x;
  if (i < R2 * 64) tsum[i] = 0.f;
  if (i < 4) { slots[2 * i] = f2o(3.402823466e38f); slots[2 * i + 1] = f2o(-3.402823466e38f); }
}

// Wn[bit][e] = W[e] + N(key_{layer,bit}, e) * |W[e]| * 0.1   (partitionable threefry)
__global__ __launch_bounds__(256) void k_gen_noise(const float* __restrict__ W, float* __restrict__ Wn,
                                                   int n, unsigned layer) {
  int t = blockIdx.x * 256 + threadIdx.x;
  int total = n * 8;
  if (t >= total) return;
  int bit = t / n;
  int e = t - bit * n;
  unsigned kl0, kl1, kb0, kb1, r0, r1;
  tf2x32(0u, 42u, 0u, layer, kl0, kl1);                 // fold_in(key(42), layer)
  tf2x32(kl0, kl1, 0u, (unsigned)bit, kb0, kb1);        // fold_in(., bit)
  tf2x32(kb0, kb1, 0u, (unsigned)e, r0, r1);            // counter-per-element
  unsigned bits = r0 ^ r1;                              // partitionable 32-bit fold
  float w = W[e];
  Wn[(size_t)bit * n + e] = w + normal_from_bits(bits) * fabsf(w) * 0.1f;
}

__global__ __launch_bounds__(256) void k_rowsum7(const float* __restrict__ Wn, float* __restrict__ rs,
                                                 int rows, int cols) {
  int o = blockIdx.x * 256 + threadIdx.x;
  if (o >= rows) return;
  const float* p = Wn + (size_t)7 * rows * cols + (size_t)o * cols;
  float s = 0.f;
  for (int j = 0; j < cols; ++j) s += p[j];
  rs[o] = s;
}

__global__ __launch_bounds__(256) void k_build_c2(const float* __restrict__ node, const float* __restrict__ mask,
                                                  const int* __restrict__ nidx, float* __restrict__ c2in,
                                                  unsigned* __restrict__ slot) {
  __shared__ float sred[512];
  int idx = blockIdx.x * 256 + threadIdx.x;
  float lmn = 3.4e38f, lmx = -3.4e38f;
  if (idx < R2 * 128) {
    int row = idx >> 7, c = idx & 127;
    float v;
    if (c < 64) v = node[(size_t)(row / 20) * 64 + c];
    else {
      int b = row / 960;
      v = node[(size_t)(b * 48 + nidx[row]) * 64 + (c - 64)] * mask[row];
    }
    c2in[idx] = v; lmn = v; lmx = v;
  }
  blockMinMax(lmn, lmx, sred, slot);
}

__global__ __launch_bounds__(256) void k_build_nk(const float* __restrict__ node, const int* __restrict__ nidx,
                                                  float* __restrict__ NK) {
  int idx = blockIdx.x * 256 + threadIdx.x;
  if (idx >= R2 * 64) return;
  int row = idx >> 6, c = idx & 63;
  int b = row / 960;
  NK[idx] = node[(size_t)(b * 48 + nidx[row]) * 64 + c];
}

__global__ __launch_bounds__(256) void k_minmax_flat(const float* __restrict__ x, int n, unsigned* __restrict__ slot) {
  __shared__ float sred[512];
  float lmn = 3.4e38f, lmx = -3.4e38f;
  for (int idx = blockIdx.x * 256 + threadIdx.x; idx < n; idx += gridDim.x * 256) {
    float v = x[idx]; lmn = fminf(lmn, v); lmx = fmaxf(lmx, v);
  }
  blockMinMax(lmn, lmx, sred, slot);
}

__global__ __launch_bounds__(256) void k_minmax_half(const float* __restrict__ c2in, unsigned* __restrict__ slot) {
  __shared__ float sred[512];
  int idx = blockIdx.x * 256 + threadIdx.x;
  float lmn = 3.4e38f, lmx = -3.4e38f;
  if (idx < R2 * 64) {
    int r = idx >> 6, c = idx & 63;
    float v = c2in[(size_t)r * 128 + 64 + c];
    lmn = v; lmx = v;
  }
  blockMinMax(lmn, lmx, sred, slot);
}

// min/max over gather-referenced node_k and edge_jk rows
__global__ __launch_bounds__(256) void k_minmax_ref3(const float* __restrict__ NK, const float* __restrict__ edge,
                                                     const int* __restrict__ nidx, unsigned* __restrict__ slot) {
  __shared__ float sred[512];
  int bij = blockIdx.x;
  int b = bij / 960;
  int jp = nidx[bij];
  size_t base = (size_t)((b * 48 + jp) * 20) * 64;
  float lmn = 3.4e38f, lmx = -3.4e38f;
  for (int t = threadIdx.x; t < 20 * 64; t += 256) {
    float v1 = NK[base + t];
    float v2 = edge[base + t];
    lmn = fminf(lmn, fminf(v1, v2));
    lmx = fmaxf(lmx, fmaxf(v1, v2));
  }
  blockMinMax(lmn, lmx, sred, slot);
}

// generic bit-serial quantized GEMM: Z[M,Nfull](+)= sum_{k,i} (q(X)&(1<<i)) * Wn_i
// tile: 32 rows x 64 cols, 256 threads (thread = 1 row x 8 cols)
__global__ __launch_bounds__(256) void k_bitgemm(
    const float* __restrict__ X, int xstride, int xcol0,
    const float* __restrict__ Wn, int Nfull, int Kfull, int wcol0,
    const unsigned* __restrict__ slot,
    float* __restrict__ Z, int K, int accflag) {
  __shared__ unsigned qs[32 * 8];
  const int tid = threadIdx.x;
  const int r = tid >> 3, cg = tid & 7;
  const int grow = blockIdx.y * 32 + r;
  const int col0 = blockIdx.x * 64 + cg * 8;
  const float mn = o2f(slot[0]), mx = o2f(slot[1]);
  const float invd = 255.0f / (mx - mn);
  float acc[8];
  #pragma unroll
  for (int c = 0; c < 8; ++c) acc[c] = 0.f;
  const float* xrow = X + (size_t)grow * xstride + xcol0;
  for (int kc = 0; kc < K; kc += 32) {
    float4 xv = *(const float4*)(xrow + kc + cg * 4);
    unsigned q0 = (unsigned)((xv.x - mn) * invd);
    unsigned q1 = (unsigned)((xv.y - mn) * invd);
    unsigned q2 = (unsigned)((xv.z - mn) * invd);
    unsigned q3 = (unsigned)((xv.w - mn) * invd);
    __syncthreads();
    qs[r * 8 + cg] = q0 | (q1 << 8) | (q2 << 16) | (q3 << 24);
    __syncthreads();
    #pragma unroll
    for (int k4 = 0; k4 < 8; ++k4) {
      unsigned qw = qs[r * 8 + k4];
      unsigned by0 = qw & 255u, by1 = (qw >> 8) & 255u, by2 = (qw >> 16) & 255u, by3 = qw >> 24;
      const float* wp0 = Wn + (size_t)col0 * Kfull + (wcol0 + kc + k4 * 4);
      #pragma unroll
      for (int i = 0; i < 8; ++i) {
        const unsigned m = 1u << i;
        float f0 = (float)(by0 & m), f1 = (float)(by1 & m), f2 = (float)(by2 & m), f3 = (float)(by3 & m);
        const float* wp = wp0 + (size_t)i * Nfull * Kfull;
        #pragma unroll
        for (int c = 0; c < 8; ++c) {
          const float4 w = *(const float4*)(wp + (size_t)c * Kfull);
          acc[c] = fmaf(f0, w.x, acc[c]);
          acc[c] = fmaf(f1, w.y, acc[c]);
          acc[c] = fmaf(f2, w.z, acc[c]);
          acc[c] = fmaf(f3, w.w, acc[c]);
        }
      }
    }
  }
  float* zp = Z + (size_t)grow * Nfull + col0;
  if (accflag) {
    #pragma unroll
    for (int c = 0; c < 8; ++c) zp[c] += acc[c];
  } else {
    #pragma unroll
    for (int c = 0; c < 8; ++c) zp[c] = acc[c];
  }
}

__global__ __launch_bounds__(256) void k_act1(const float* __restrict__ z1, const float* __restrict__ rs,
                                              const unsigned* __restrict__ slot0, float* __restrict__ c2b,
                                              unsigned* __restrict__ slot1) {
  __shared__ float sred[512];
  const float mn = o2f(slot0[0]), mx = o2f(slot0[1]);
  int idx = blockIdx.x * 256 + threadIdx.x;
  float lmn = 3.4e38f, lmx = -3.4e38f;
  if (idx < R2 * 512) {
    int o = idx & 511;
    float v = fmaxf(0.f, z1[idx] * (1.f / 255.f) * (mx - mn) + mn * rs[o]);
    c2b[idx] = v; lmn = v; lmx = v;
  }
  blockMinMax(lmn, lmx, sred, slot1);
}

__global__ __launch_bounds__(256) void k_act2(const float* __restrict__ z2, const float* __restrict__ rs,
                                              const unsigned* __restrict__ slot, float* __restrict__ two) {
  int idx = blockIdx.x * 256 + threadIdx.x;
  if (idx >= R2 * 64) return;
  const float mn = o2f(slot[0]), mx = o2f(slot[1]);
  int row = idx >> 6, c = idx & 63;
  float d = (mx - mn) * (1.f / 255.f);
  float g = z2[(size_t)row * 128 + c] * d + mn * rs[c];
  float e = z2[(size_t)row * 128 + 64 + c] * d + mn * rs[64 + c];
  two[idx] = (1.f / (1.f + expf(-g))) * tanhf(e);
}

__global__ __launch_bounds__(256) void k_minmax_c3b(
    const float* __restrict__ P1, const float* __restrict__ P2, const float* __restrict__ P3,
    const float* __restrict__ rs3a, const int* __restrict__ nidx,
    const unsigned* __restrict__ slot2, unsigned* __restrict__ slot3) {
  __shared__ float sred[512];
  const float mn2 = o2f(slot2[0]), mx2 = o2f(slot2[1]);
  const float sc2 = (mx2 - mn2) * (1.f / 255.f);
  float lmn = 3.4e38f, lmx = -3.4e38f;
  for (int idx = blockIdx.x * 256 + threadIdx.x; idx < M4 * 640; idx += gridDim.x * 256) {
    int srow = idx / 640;
    int k = idx - srow * 640;
    int bij = srow / 20;
    int knb = srow - bij * 20;
    int b = bij / 960;
    int p3row = (b * 48 + nidx[bij]) * 20 + knb;
    int p1row = bij / 20;
    float z3 = P1[(size_t)p1row * 640 + k] + P2[(size_t)bij * 640 + k] + P3[(size_t)p3row * 640 + k];
    float v = fmaxf(0.f, z3 * sc2 + mn2 * rs3a[k]);
    lmn = fminf(lmn, v); lmx = fmaxf(lmx, v);
  }
  blockMinMax(lmn, lmx, sred, slot3);
}

// fused 3-body second qmm: A-row built from P1+P2+P3 (requant+relu+quant),
// epilogue: requant -> sigmoid*tanh -> mask -> atomic k-sum into tsum
__global__ __launch_bounds__(256) void k_bitgemm4(
    const float* __restrict__ P1, const float* __restrict__ P2, const float* __restrict__ P3,
    const float* __restrict__ rs3a, const float* __restrict__ rs3b,
    const float* __restrict__ Wn,
    const int* __restrict__ nidx, const float* __restrict__ mask,
    const unsigned* __restrict__ slot2, const unsigned* __restrict__ slot3,
    float* __restrict__ tsum) {
  __shared__ float zbuf[32 * 128];
  unsigned* qs = (unsigned*)zbuf;
  const int tid = threadIdx.x;
  const int r = tid >> 3, cg = tid & 7;
  const int s = blockIdx.x * 32 + r;
  const int bij = s / 20;
  const int knb = s - bij * 20;
  const int b = bij / 960;
  const int jp = nidx[bij];
  const int p3row = (b * 48 + jp) * 20 + knb;
  const int p1row = bij / 20;
  const float mn2 = o2f(slot2[0]), mx2 = o2f(slot2[1]);
  const float mn3 = o2f(slot3[0]), mx3 = o2f(slot3[1]);
  const float sc2 = (mx2 - mn2) * (1.0f / 255.0f);
  const float invd3 = 255.0f / (mx3 - mn3);
  const float* p1p = P1 + (size_t)p1row * 640;
  const float* p2p = P2 + (size_t)bij * 640;
  const float* p3p = P3 + (size_t)p3row * 640;
  float acc[16];
  #pragma unroll
  for (int c = 0; c < 16; ++c) acc[c] = 0.f;
  for (int kc = 0; kc < 640; kc += 32) {
    int k0 = kc + cg * 4;
    unsigned qq = 0;
    #pragma unroll
    for (int kk = 0; kk < 4; ++kk) {
      int k = k0 + kk;
      float z3 = p1p[k] + p2p[k] + p3p[k];
      float v = fmaxf(0.f, z3 * sc2 + mn2 * rs3a[k]);
      unsigned q = (unsigned)((v - mn3) * invd3);
      qq |= q << (kk * 8);
    }
    __syncthreads();
    qs[r * 8 + cg] = qq;
    __syncthreads();
    #pragma unroll
    for (int k4 = 0; k4 < 8; ++k4) {
      unsigned qw = qs[r * 8 + k4];
      unsigned by0 = qw & 255u, by1 = (qw >> 8) & 255u, by2 = (qw >> 16) & 255u, by3 = qw >> 24;
      const float* wp0 = Wn + (size_t)(cg * 16) * 640 + kc + k4 * 4;
      #pragma unroll
      for (int i = 0; i < 8; ++i) {
        const unsigned m = 1u << i;
        float f0 = (float)(by0 & m), f1 = (float)(by1 & m), f2 = (float)(by2 & m), f3 = (float)(by3 & m);
        const float* wp = wp0 + (size_t)i * (128 * 640);
        #pragma unroll
        for (int c = 0; c < 16; ++c) {
          const float4 w = *(const float4*)(wp + (size_t)c * 640);
          acc[c] = fmaf(f0, w.x, acc[c]);
          acc[c] = fmaf(f1, w.y, acc[c]);
          acc[c] = fmaf(f2, w.z, acc[c]);
          acc[c] = fmaf(f3, w.w, acc[c]);
        }
      }
    }
  }
  __syncthreads();
  #pragma unroll
  for (int c = 0; c < 16; ++c) zbuf[r * 128 + cg * 16 + c] = acc[c];
  __syncthreads();
  const float d3 = (mx3 - mn3) * (1.0f / 255.0f);
  for (int e = tid; e < 32 * 64; e += 256) {
    int rr = e >> 6, c = e & 63;
    int ss2 = blockIdx.x * 32 + rr;
    int bij2 = ss2 / 20, knb2 = ss2 - bij2 * 20, b2 = bij2 / 960;
    int jp2 = nidx[bij2];
    int p3r = (b2 * 48 + jp2) * 20 + knb2;
    float g = zbuf[rr * 128 + c] * d3 + mn3 * rs3b[c];
    float eo = zbuf[rr * 128 + 64 + c] * d3 + mn3 * rs3b[64 + c];
    float val = (1.f / (1.f + expf(-g))) * tanhf(eo) * mask[p3r];
    atomicAdd(&tsum[(size_t)bij2 * 64 + c], val);
  }
}

__global__ __launch_bounds__(256) void k_bnstats(const float* __restrict__ x, float* __restrict__ mout,
                                                 float* __restrict__ vout) {
  __shared__ float ss[512];
  int c = blockIdx.x, t = threadIdx.x;
  float s = 0.f, q = 0.f;
  for (int r = t; r < R2; r += 256) { float v = x[(size_t)r * 64 + c]; s += v; q += v * v; }
  ss[t] = s; ss[256 + t] = q;
  __syncthreads();
  for (int st = 128; st > 0; st >>= 1) {
    if (t < st) { ss[t] += ss[t + st]; ss[256 + t] += ss[256 + t + st]; }
    __syncthreads();
  }
  if (t == 0) { float m = ss[0] / (float)R2; mout[c] = m; vout[c] = ss[256] / (float)R2 - m * m; }
}

__global__ __launch_bounds__(256) void k_final(const float* __restrict__ edge, const float* __restrict__ two,
                                               const float* __restrict__ tsum, const float* __restrict__ bn,
                                               const float* __restrict__ g2, const float* __restrict__ b2,
                                               const float* __restrict__ g3, const float* __restrict__ b3,
                                               float* __restrict__ out) {
  int idx = blockIdx.x * 256 + threadIdx.x;
  if (idx >= R2 * 64) return;
  int c = idx & 63;
  float t2 = (two[idx] - bn[c]) / sqrtf(bn[64 + c] + 1e-5f) * g2[c] + b2[c];
  float t3 = (tsum[idx] - bn[128 + c]) / sqrtf(bn[192 + c] + 1e-5f) * g3[c] + b3[c];
  out[idx] = fmaxf(0.f, edge[idx] + t2 + t3);
}

// ---------------- host launcher ----------------
extern "C" void kernel_launch(void* const* d_in, const int* in_sizes, int n_in,
                              void* d_out, int out_size, void* d_ws, size_t ws_size,
                              hipStream_t stream) {
  (void)in_sizes; (void)n_in; (void)out_size; (void)ws_size;
  const float* node   = (const float*)d_in[0];
  const float* edge   = (const float*)d_in[1];
  const float* mask   = (const float*)d_in[2];
  const float* c_two  = (const float*)d_in[3];
  const float* c_two2 = (const float*)d_in[4];
  const float* c_three  = (const float*)d_in[5];
  const float* c_three2 = (const float*)d_in[6];
  const float* bn2g = (const float*)d_in[7];
  const float* bn2b = (const float*)d_in[8];
  const float* bn3g = (const float*)d_in[9];
  const float* bn3b = (const float*)d_in[10];
  const int*   nidx = (const int*)d_in[11];
  float* ws = (float*)d_ws;
  unsigned* slots = (unsigned*)(ws + OFF_SLOT);
  float* out = (float*)d_out;

  k_init<<<960, 256, 0, stream>>>(ws + OFF_TSUM, slots);

  k_gen_noise<<<(8 * 65536 + 255) / 256, 256, 0, stream>>>(c_two,   ws + OFF_WN2A, 65536, 0u);
  k_gen_noise<<<(8 * 65536 + 255) / 256, 256, 0, stream>>>(c_two2,  ws + OFF_WN2B, 65536, 1u);
  k_gen_noise<<<(8 * 204800 + 255) / 256, 256, 0, stream>>>(c_three, ws + OFF_WN3A, 204800, 2u);
  k_gen_noise<<<(8 * 81920 + 255) / 256, 256, 0, stream>>>(c_three2, ws + OFF_WN3B, 81920, 3u);

  k_rowsum7<<<2, 256, 0, stream>>>(ws + OFF_WN2A, ws + OFF_RS2A, 512, 128);
  k_rowsum7<<<1, 256, 0, stream>>>(ws + OFF_WN2B, ws + OFF_RS2B, 128, 512);
  k_rowsum7<<<3, 256, 0, stream>>>(ws + OFF_WN3A, ws + OFF_RS3A, 640, 320);
  k_rowsum7<<<1, 256, 0, stream>>>(ws + OFF_WN3B, ws + OFF_RS3B, 128, 640);

  // two-body
  k_build_c2<<<1920, 256, 0, stream>>>(node, mask, nidx, ws + OFF_C2IN, slots + 0);
  k_bitgemm<<<dim3(8, 120), 256, 0, stream>>>(ws + OFF_C2IN, 128, 0, ws + OFF_WN2A, 512, 128, 0,
                                              slots + 0, ws + OFF_Z1, 128, 0);
  k_act1<<<7680, 256, 0, stream>>>(ws + OFF_Z1, ws + OFF_RS2A, slots + 0, ws + OFF_C2B, slots + 2);
  k_bitgemm<<<dim3(2, 120), 256, 0, stream>>>(ws + OFF_C2B, 512, 0, ws + OFF_WN2B, 128, 512, 0,
                                              slots + 2, ws + OFF_Z2, 512, 0);
  k_act2<<<960, 256, 0, stream>>>(ws + OFF_Z2, ws + OFF_RS2B, slots + 2, ws + OFF_TWO);

  // three-body: min/max of c3 (piecewise), P1/P2/P3 decomposition
  k_build_nk<<<960, 256, 0, stream>>>(node, nidx, ws + OFF_NK);
  k_minmax_flat<<<48, 256, 0, stream>>>(node, B_ * AT * 64, slots + 4);
  k_minmax_flat<<<960, 256, 0, stream>>>(edge, R2 * 64, slots + 4);
  k_minmax_half<<<960, 256, 0, stream>>>(ws + OFF_C2IN, slots + 4);
  k_minmax_ref3<<<3840, 256, 0, stream>>>(ws + OFF_NK, edge, nidx, slots + 4);

  k_bitgemm<<<dim3(10, 6), 256, 0, stream>>>(node, 64, 0, ws + OFF_WN3A, 640, 320, 0,
                                             slots + 4, ws + OFF_P1, 64, 0);
  k_bitgemm<<<dim3(10, 120), 256, 0, stream>>>(ws + OFF_C2IN, 128, 64, ws + OFF_WN3A, 640, 320, 64,
                                               slots + 4, ws + OFF_P2, 64, 0);
  k_bitgemm<<<dim3(10, 120), 256, 0, stream>>>(edge, 64, 0, ws + OFF_WN3A, 640, 320, 192,
                                               slots + 4, ws + OFF_P2, 64, 1);
  k_bitgemm<<<dim3(10, 120), 256, 0, stream>>>(ws + OFF_NK, 64, 0, ws + OFF_WN3A, 640, 320, 128,
                                               slots + 4, ws + OFF_P3, 64, 0);
  k_bitgemm<<<dim3(10, 120), 256, 0, stream>>>(edge, 64, 0, ws + OFF_WN3A, 640, 320, 256,
                                               slots + 4, ws + OFF_P3, 64, 1);

  k_minmax_c3b<<<4096, 256, 0, stream>>>(ws + OFF_P1, ws + OFF_P2, ws + OFF_P3, ws + OFF_RS3A,
                                         nidx, slots + 4, slots + 6);
  k_bitgemm4<<<2400, 256, 0, stream>>>(ws + OFF_P1, ws + OFF_P2, ws + OFF_P3, ws + OFF_RS3A, ws + OFF_RS3B,
                                       ws + OFF_WN3B, nidx, mask, slots + 4, slots + 6, ws + OFF_TSUM);

  k_bnstats<<<64, 256, 0, stream>>>(ws + OFF_TWO, ws + OFF_BN + 0, ws + OFF_BN + 64);
  k_bnstats<<<64, 256, 0, stream>>>(ws + OFF_TSUM, ws + OFF_BN + 128, ws + OFF_BN + 192);
  k_final<<<960, 256, 0, stream>>>(edge, ws + OFF_TWO, ws + OFF_TSUM, ws + OFF_BN,
                                   bn2g, bn2b, bn3g, bn3b, out);
}

// Round 2
// 3003.020 us; speedup vs baseline: 9.4935x; 9.4935x over previous
//
#include <hip/hip_runtime.h>
#include <cstdint>
#include <cstddef>

#define DEVI __device__ __forceinline__

typedef __attribute__((ext_vector_type(8))) short s8v;   // 8 bf16 bit patterns
typedef __attribute__((ext_vector_type(4))) float f4v;

static constexpr int B_ = 4, AT = 48, NBRS = 20;
static constexpr int R2 = B_ * AT * NBRS;   // 3840 (b,i,j) rows
static constexpr int M4 = R2 * NBRS;        // 76800 (b,i,j,k) rows

// ---------------- workspace layout (float offsets) ----------------
static constexpr size_t OFF_B2AH = 0;                         // 512x1024 sh
static constexpr size_t OFF_B2AL = OFF_B2AH + 262144;
static constexpr size_t OFF_B2BH = OFF_B2AL + 262144;         // 128x4096 sh
static constexpr size_t OFF_B2BL = OFF_B2BH + 262144;
static constexpr size_t OFF_B3AH = OFF_B2BL + 262144;         // 640x2560 sh
static constexpr size_t OFF_B3AL = OFF_B3AH + 819200;
static constexpr size_t OFF_B3BH = OFF_B3AL + 819200;         // 128x5120 sh
static constexpr size_t OFF_B3BL = OFF_B3BH + 327680;
static constexpr size_t OFF_W72A = OFF_B3BL + 327680;         // 512x128 f
static constexpr size_t OFF_W72B = OFF_W72A + 65536;          // 128x512 f
static constexpr size_t OFF_W73A = OFF_W72B + 65536;          // 640x320 f
static constexpr size_t OFF_W73B = OFF_W73A + 204800;         // 128x640 f
static constexpr size_t OFF_RS2A = OFF_W73B + 81920;          // 512
static constexpr size_t OFF_RS2B = OFF_RS2A + 512;            // 128
static constexpr size_t OFF_RS3A = OFF_RS2B + 128;            // 640
static constexpr size_t OFF_RS3B = OFF_RS3A + 640;            // 128
static constexpr size_t OFF_SLOT = OFF_RS3B + 128;            // 16 (8 u32 used)
static constexpr size_t OFF_BN   = OFF_SLOT + 16;             // 256
static constexpr size_t OFF_C2IN = OFF_BN + 256;              // 3840x128
static constexpr size_t OFF_Z1   = OFF_C2IN + (size_t)R2 * 128;
static constexpr size_t OFF_C2B  = OFF_Z1 + (size_t)R2 * 512;
static constexpr size_t OFF_Z2   = OFF_C2B + (size_t)R2 * 512;
static constexpr size_t OFF_TWO  = OFF_Z2 + (size_t)R2 * 128;
static constexpr size_t OFF_NK   = OFF_TWO + (size_t)R2 * 64;
static constexpr size_t OFF_P1   = OFF_NK + (size_t)R2 * 64;   // 192x640
static constexpr size_t OFF_P2   = OFF_P1 + (size_t)192 * 640;
static constexpr size_t OFF_P3   = OFF_P2 + (size_t)R2 * 640;
static constexpr size_t OFF_TSUM = OFF_P3 + (size_t)R2 * 640;
static constexpr size_t OFF_Q2A  = OFF_TSUM + (size_t)R2 * 64; // bytes/4 sizes
static constexpr size_t OFF_Q2B  = OFF_Q2A + 122880;
static constexpr size_t OFF_QND  = OFF_Q2B + 491520;
static constexpr size_t OFF_QC2  = OFF_QND + 3072;
static constexpr size_t OFF_QED  = OFF_QC2 + 61440;
static constexpr size_t OFF_QNK  = OFF_QED + 61440;

// ---------------- threefry-2x32 (JAX-compatible, verified round 1) ----------------
DEVI void tf2x32(unsigned k0, unsigned k1, unsigned x0, unsigned x1,
                 unsigned& o0, unsigned& o1) {
  unsigned ks0 = k0, ks1 = k1, ks2 = k0 ^ k1 ^ 0x1BD11BDAu;
  x0 += ks0; x1 += ks1;
  const unsigned rotA[4] = {13u, 15u, 26u, 6u};
  const unsigned rotB[4] = {17u, 29u, 16u, 24u};
  unsigned ks[3] = {ks0, ks1, ks2};
  #pragma unroll
  for (int i = 0; i < 5; ++i) {
    const unsigned* rot = (i & 1) ? rotB : rotA;
    #pragma unroll
    for (int r = 0; r < 4; ++r) {
      x0 += x1;
      x1 = (x1 << rot[r]) | (x1 >> (32u - rot[r]));
      x1 ^= x0;
    }
    x0 += ks[(i + 1) % 3];
    x1 += ks[(i + 2) % 3] + (unsigned)(i + 1);
  }
  o0 = x0; o1 = x1;
}

DEVI float erfinv_xla(float x) {
  float w = -log1pf(-x * x);
  float p;
  if (w < 5.f) {
    w -= 2.5f;
    p = 2.81022636e-08f;
    p = fmaf(p, w, 3.43273939e-07f);
    p = fmaf(p, w, -3.5233877e-06f);
    p = fmaf(p, w, -4.39150654e-06f);
    p = fmaf(p, w, 0.00021858087f);
    p = fmaf(p, w, -0.00125372503f);
    p = fmaf(p, w, -0.00417768164f);
    p = fmaf(p, w, 0.246640727f);
    p = fmaf(p, w, 1.50140941f);
  } else {
    w = sqrtf(w) - 3.f;
    p = -0.000200214257f;
    p = fmaf(p, w, 0.000100950558f);
    p = fmaf(p, w, 0.00134934322f);
    p = fmaf(p, w, -0.00367342844f);
    p = fmaf(p, w, 0.00573950773f);
    p = fmaf(p, w, -0.0076224613f);
    p = fmaf(p, w, 0.00943887047f);
    p = fmaf(p, w, 1.00167406f);
    p = fmaf(p, w, 2.83297682f);
  }
  return p * x;
}

DEVI float normal_from_bits(unsigned bits) {
  unsigned fb = (bits >> 9) | 0x3F800000u;
  float f = __uint_as_float(fb) - 1.0f;
  const float lo = -0.99999994f;
  float u = f * (1.0f - lo) + lo;
  u = fmaxf(lo, u);
  return 1.41421356237f * erfinv_xla(u);
}

DEVI unsigned f2o(float f) { unsigned u = __float_as_uint(f); return (u & 0x80000000u) ? ~u : (u | 0x80000000u); }
DEVI float o2f(unsigned u) { return (u & 0x80000000u) ? __uint_as_float(u & 0x7FFFFFFFu) : __uint_as_float(~u); }

DEVI unsigned short f2bf(float x) {  // RNE f32 -> bf16
  unsigned u = __float_as_uint(x);
  return (unsigned short)((u + 0x7FFFu + ((u >> 16) & 1u)) >> 16);
}
DEVI float bf2f(unsigned short h) { return __uint_as_float((unsigned)h << 16); }

DEVI void blockMinMax(float lmn, float lmx, float* smem, unsigned* slot) {
  float* smn = smem; float* smx = smem + 256;
  int t = threadIdx.x;
  smn[t] = lmn; smx[t] = lmx;
  __syncthreads();
  for (int s = 128; s > 0; s >>= 1) {
    if (t < s) { smn[t] = fminf(smn[t], smn[t + s]); smx[t] = fmaxf(smx[t], smx[t + s]); }
    __syncthreads();
  }
  if (t == 0) { atomicMin(slot + 0, f2o(smn[0])); atomicMax(slot + 1, f2o(smx[0])); }
}

DEVI s8v expand_bits(unsigned b) {
  s8v f;
  #pragma unroll
  for (int j = 0; j < 8; ++j) f[j] = (short)(((b >> j) & 1u) ? 0x3F80 : 0);
  return f;
}

// ---------------- kernels ----------------
__global__ __launch_bounds__(256) void k_init(float* __restrict__ tsum, unsigned* __restrict__ slots) {
  int i = blockIdx.x * 256 + threadIdx.x;
  if (i < R2 * 64) tsum[i] = 0.f;
  if (i < 4) { slots[2 * i] = f2o(3.402823466e38f); slots[2 * i + 1] = f2o(-3.402823466e38f); }
}

// Expanded noisy weights: Bhi/Blo[n][k*8+bit] = bf16split(2^bit * (W + N*|W|*0.1)); Wn7 = bit-7 noisy W (f32)
__global__ __launch_bounds__(256) void k_gen_wexp(const float* __restrict__ W, int N, int K, unsigned layer,
                                                  short* __restrict__ Bhi, short* __restrict__ Blo,
                                                  float* __restrict__ Wn7) {
  int t = blockIdx.x * 256 + threadIdx.x;
  int n_elem = N * K;
  if (t >= n_elem * 8) return;
  int bit = t / n_elem;
  int e = t - bit * n_elem;
  unsigned kl0, kl1, kb0, kb1, r0, r1;
  tf2x32(0u, 42u, 0u, layer, kl0, kl1);
  tf2x32(kl0, kl1, 0u, (unsigned)bit, kb0, kb1);
  tf2x32(kb0, kb1, 0u, (unsigned)e, r0, r1);
  float w = W[e];
  float wn = w + normal_from_bits(r0 ^ r1) * fabsf(w) * 0.1f;
  float sv = ldexpf(wn, bit);
  unsigned short hi = f2bf(sv);
  unsigned short lo = f2bf(sv - bf2f(hi));
  int n = e / K, k = e - n * K;
  size_t off = (size_t)n * ((size_t)K * 8) + (size_t)k * 8 + bit;
  Bhi[off] = (short)hi; Blo[off] = (short)lo;
  if (bit == 7) Wn7[e] = wn;
}

__global__ __launch_bounds__(256) void k_rowsum(const float* __restrict__ Wn7, float* __restrict__ rs,
                                                int rows, int cols) {
  int o = blockIdx.x * 256 + threadIdx.x;
  if (o >= rows) return;
  const float* p = Wn7 + (size_t)o * cols;
  float s = 0.f;
  for (int j = 0; j < cols; ++j) s += p[j];
  rs[o] = s;
}

__global__ __launch_bounds__(256) void k_build_c2(const float* __restrict__ node, const float* __restrict__ mask,
                                                  const int* __restrict__ nidx, float* __restrict__ c2in,
                                                  unsigned* __restrict__ slot) {
  __shared__ float sred[512];
  int idx = blockIdx.x * 256 + threadIdx.x;
  float lmn = 3.4e38f, lmx = -3.4e38f;
  if (idx < R2 * 128) {
    int row = idx >> 7, c = idx & 127;
    float v;
    if (c < 64) v = node[(size_t)(row / 20) * 64 + c];
    else {
      int b = row / 960;
      v = node[(size_t)(b * 48 + nidx[row]) * 64 + (c - 64)] * mask[row];
    }
    c2in[idx] = v; lmn = v; lmx = v;
  }
  blockMinMax(lmn, lmx, sred, slot);
}

__global__ __launch_bounds__(256) void k_build_nk(const float* __restrict__ node, const int* __restrict__ nidx,
                                                  float* __restrict__ NK) {
  int idx = blockIdx.x * 256 + threadIdx.x;
  if (idx >= R2 * 64) return;
  int row = idx >> 6, c = idx & 63;
  int b = row / 960;
  NK[idx] = node[(size_t)(b * 48 + nidx[row]) * 64 + c];
}

__global__ __launch_bounds__(256) void k_minmax_flat(const float* __restrict__ x, int n, unsigned* __restrict__ slot) {
  __shared__ float sred[512];
  float lmn = 3.4e38f, lmx = -3.4e38f;
  for (int idx = blockIdx.x * 256 + threadIdx.x; idx < n; idx += gridDim.x * 256) {
    float v = x[idx]; lmn = fminf(lmn, v); lmx = fmaxf(lmx, v);
  }
  blockMinMax(lmn, lmx, sred, slot);
}

__global__ __launch_bounds__(256) void k_minmax_half(const float* __restrict__ c2in, unsigned* __restrict__ slot) {
  __shared__ float sred[512];
  int idx = blockIdx.x * 256 + threadIdx.x;
  float lmn = 3.4e38f, lmx = -3.4e38f;
  if (idx < R2 * 64) {
    int r = idx >> 6, c = idx & 63;
    float v = c2in[(size_t)r * 128 + 64 + c];
    lmn = v; lmx = v;
  }
  blockMinMax(lmn, lmx, sred, slot);
}

__global__ __launch_bounds__(256) void k_minmax_ref3(const float* __restrict__ NK, const float* __restrict__ edge,
                                                     const int* __restrict__ nidx, unsigned* __restrict__ slot) {
  __shared__ float sred[512];
  int bij = blockIdx.x;
  int b = bij / 960;
  int jp = nidx[bij];
  size_t base = (size_t)((b * 48 + jp) * 20) * 64;
  float lmn = 3.4e38f, lmx = -3.4e38f;
  for (int t = threadIdx.x; t < 20 * 64; t += 256) {
    float v1 = NK[base + t];
    float v2 = edge[base + t];
    lmn = fminf(lmn, fminf(v1, v2));
    lmx = fmaxf(lmx, fmaxf(v1, v2));
  }
  blockMinMax(lmn, lmx, sred, slot);
}

__global__ __launch_bounds__(256) void k_quant(const float* __restrict__ X, int ld, int col0,
                                               int rows, int cols, const unsigned* __restrict__ slot,
                                               unsigned char* __restrict__ Q) {
  int idx = blockIdx.x * 256 + threadIdx.x;
  if (idx >= rows * cols) return;
  int r = idx / cols, c = idx - r * cols;
  const float mn = o2f(slot[0]), mx = o2f(slot[1]);
  float invd = 255.f / (mx - mn);
  Q[idx] = (unsigned char)((X[(size_t)r * ld + col0 + c] - mn) * invd);
}

// Generic MFMA bit-serial GEMM: Z[M][Nfull] (+)= A'(Q bits) x B'(hi+lo)
// block 128x128, 4 waves in 2x2, wave = 64 rows x 64 cols (4 m-frags x 4 n-frags)
__global__ __launch_bounds__(256) void k_mfma_gemm(
    const unsigned char* __restrict__ Q, int ldq,
    const short* __restrict__ Bhi, const short* __restrict__ Blo, int ldb, int kp0,
    int M, int Nfull, int KB, float* __restrict__ Z, int accflag) {
  const int tid = threadIdx.x;
  const int lane = tid & 63, wave = tid >> 6;
  const int wr = wave >> 1, wc = wave & 1;
  const int l15 = lane & 15, l4 = lane >> 4;
  const int mbase = blockIdx.y * 128 + wr * 64;
  const int nbase = blockIdx.x * 128 + wc * 64;
  f4v acc[4][4];
  #pragma unroll
  for (int a = 0; a < 4; ++a)
    #pragma unroll
    for (int b = 0; b < 4; ++b) acc[a][b] = f4v{0.f, 0.f, 0.f, 0.f};
  for (int ks = 0; ks < KB; ks += 4) {
    s8v af[4];
    #pragma unroll
    for (int mf = 0; mf < 4; ++mf) {
      int row = mbase + mf * 16 + l15; if (row >= M) row = M - 1;
      unsigned w = *(const unsigned*)(Q + (size_t)row * ldq + ks);
      af[mf] = expand_bits((w >> (l4 * 8)) & 255u);
    }
    #pragma unroll
    for (int nf = 0; nf < 4; ++nf) {
      size_t boff = (size_t)(nbase + nf * 16 + l15) * ldb + kp0 + ks * 8 + l4 * 8;
      s8v bh = *(const s8v*)(Bhi + boff);
      s8v bl = *(const s8v*)(Blo + boff);
      #pragma unroll
      for (int mf = 0; mf < 4; ++mf) {
        acc[mf][nf] = __builtin_amdgcn_mfma_f32_16x16x32_bf16(af[mf], bh, acc[mf][nf], 0, 0, 0);
        acc[mf][nf] = __builtin_amdgcn_mfma_f32_16x16x32_bf16(af[mf], bl, acc[mf][nf], 0, 0, 0);
      }
    }
  }
  #pragma unroll
  for (int mf = 0; mf < 4; ++mf) {
    #pragma unroll
    for (int r = 0; r < 4; ++r) {
      int m = mbase + mf * 16 + l4 * 4 + r;
      if (m >= M) continue;
      float* zp = Z + (size_t)m * Nfull + nbase;
      #pragma unroll
      for (int nf = 0; nf < 4; ++nf) {
        int n = nf * 16 + l15;
        if (accflag) zp[n] += acc[mf][nf][r]; else zp[n] = acc[mf][nf][r];
      }
    }
  }
}

__global__ __launch_bounds__(256) void k_act1(const float* __restrict__ z1, const float* __restrict__ rs,
                                              const unsigned* __restrict__ slot0, float* __restrict__ c2b,
                                              unsigned* __restrict__ slot1) {
  __shared__ float sred[512];
  const float mn = o2f(slot0[0]), mx = o2f(slot0[1]);
  int idx = blockIdx.x * 256 + threadIdx.x;
  float lmn = 3.4e38f, lmx = -3.4e38f;
  if (idx < R2 * 512) {
    int o = idx & 511;
    float v = fmaxf(0.f, z1[idx] * (1.f / 255.f) * (mx - mn) + mn * rs[o]);
    c2b[idx] = v; lmn = v; lmx = v;
  }
  blockMinMax(lmn, lmx, sred, slot1);
}

__global__ __launch_bounds__(256) void k_act2(const float* __restrict__ z2, const float* __restrict__ rs,
                                              const unsigned* __restrict__ slot, float* __restrict__ two) {
  int idx = blockIdx.x * 256 + threadIdx.x;
  if (idx >= R2 * 64) return;
  const float mn = o2f(slot[0]), mx = o2f(slot[1]);
  int row = idx >> 6, c = idx & 63;
  float d = (mx - mn) * (1.f / 255.f);
  float g = z2[(size_t)row * 128 + c] * d + mn * rs[c];
  float e = z2[(size_t)row * 128 + 64 + c] * d + mn * rs[64 + c];
  two[idx] = (1.f / (1.f + expf(-g))) * tanhf(e);
}

__global__ __launch_bounds__(256) void k_minmax_c3b(
    const float* __restrict__ P1, const float* __restrict__ P2, const float* __restrict__ P3,
    const float* __restrict__ rs3a, const int* __restrict__ nidx,
    const unsigned* __restrict__ slot2, unsigned* __restrict__ slot3) {
  __shared__ float sred[512];
  const float mn2 = o2f(slot2[0]), mx2 = o2f(slot2[1]);
  const float sc2 = (mx2 - mn2) * (1.f / 255.f);
  float lmn = 3.4e38f, lmx = -3.4e38f;
  for (int idx = blockIdx.x * 256 + threadIdx.x; idx < M4 * 640; idx += gridDim.x * 256) {
    int srow = idx / 640;
    int k = idx - srow * 640;
    int bij = srow / 20;
    int knb = srow - bij * 20;
    int b = bij / 960;
    int p3row = (b * 48 + nidx[bij]) * 20 + knb;
    int p1row = bij / 20;
    float z3 = P1[(size_t)p1row * 640 + k] + P2[(size_t)bij * 640 + k] + P3[(size_t)p3row * 640 + k];
    float v = fmaxf(0.f, z3 * sc2 + mn2 * rs3a[k]);
    lmn = fminf(lmn, v); lmx = fmaxf(lmx, v);
  }
  blockMinMax(lmn, lmx, sred, slot3);
}

// Fused 3-body second layer: LDS A-tile build (requant+relu+quant from P1+P2+P3),
// MFMA over K'=5120, in-register epilogue (sigmoid*tanh*mask) + atomic k-sum.
// block = 128 rows x 128 cols; 4 waves stacked in m (wave: 32 rows, mf 2, nf 8)
__global__ __launch_bounds__(256) void k_mfma_l3b(
    const float* __restrict__ P1, const float* __restrict__ P2, const float* __restrict__ P3,
    const float* __restrict__ rs3a, const float* __restrict__ rs3b,
    const short* __restrict__ Bhi, const short* __restrict__ Blo,
    const int* __restrict__ nidx, const float* __restrict__ mask,
    const unsigned* __restrict__ slotA, const unsigned* __restrict__ slotB,
    float* __restrict__ tsum) {
  __shared__ unsigned char qt[128 * 648];   // padded row stride: banks spread
  const int tid = threadIdx.x;
  const int s0 = blockIdx.x * 128;
  const float mn2 = o2f(slotA[0]), mx2 = o2f(slotA[1]);
  const float mn3 = o2f(slotB[0]), mx3 = o2f(slotB[1]);
  const float sc2 = (mx2 - mn2) * (1.f / 255.f);
  const float invd3 = 255.f / (mx3 - mn3);
  {
    int r = tid & 127, kh = tid >> 7;   // 2 threads per row, 320 k each
    int s = s0 + r;
    int bij = s / 20, knb = s - bij * 20, b = bij / 960;
    int p3row = (b * 48 + nidx[bij]) * 20 + knb;
    int p1row = bij / 20;
    const float* p1p = P1 + (size_t)p1row * 640;
    const float* p2p = P2 + (size_t)bij * 640;
    const float* p3p = P3 + (size_t)p3row * 640;
    for (int k = kh * 320; k < kh * 320 + 320; k += 4) {
      unsigned pk = 0;
      #pragma unroll
      for (int kk = 0; kk < 4; ++kk) {
        float v = fmaxf(0.f, (p1p[k + kk] + p2p[k + kk] + p3p[k + kk]) * sc2 + mn2 * rs3a[k + kk]);
        unsigned q = (unsigned)((v - mn3) * invd3);
        pk |= q << (kk * 8);
      }
      *(unsigned*)(&qt[(size_t)r * 648 + k]) = pk;
    }
  }
  __syncthreads();
  const int lane = tid & 63, wave = tid >> 6;
  const int l15 = lane & 15, l4 = lane >> 4;
  f4v acc[2][8];
  #pragma unroll
  for (int a = 0; a < 2; ++a)
    #pragma unroll
    for (int b = 0; b < 8; ++b) acc[a][b] = f4v{0.f, 0.f, 0.f, 0.f};
  for (int ks = 0; ks < 640; ks += 4) {
    s8v af[2];
    #pragma unroll
    for (int mf = 0; mf < 2; ++mf) {
      unsigned w = *(const unsigned*)(&qt[(size_t)(wave * 32 + mf * 16 + l15) * 648 + ks]);
      af[mf] = expand_bits((w >> (l4 * 8)) & 255u);
    }
    #pragma unroll
    for (int nf = 0; nf < 8; ++nf) {
      size_t boff = (size_t)(nf * 16 + l15) * 5120 + ks * 8 + l4 * 8;
      s8v bh = *(const s8v*)(Bhi + boff);
      s8v bl = *(const s8v*)(Blo + boff);
      #pragma unroll
      for (int mf = 0; mf < 2; ++mf) {
        acc[mf][nf] = __builtin_amdgcn_mfma_f32_16x16x32_bf16(af[mf], bh, acc[mf][nf], 0, 0, 0);
        acc[mf][nf] = __builtin_amdgcn_mfma_f32_16x16x32_bf16(af[mf], bl, acc[mf][nf], 0, 0, 0);
      }
    }
  }
  const float d3 = (mx3 - mn3) * (1.f / 255.f);
  float rg[4], re[4];
  #pragma unroll
  for (int nf = 0; nf < 4; ++nf) {
    rg[nf] = mn3 * rs3b[nf * 16 + l15];
    re[nf] = mn3 * rs3b[64 + nf * 16 + l15];
  }
  #pragma unroll
  for (int mf = 0; mf < 2; ++mf) {
    #pragma unroll
    for (int r = 0; r < 4; ++r) {
      int s = s0 + wave * 32 + mf * 16 + l4 * 4 + r;
      int bij = s / 20, knb = s - bij * 20, b = bij / 960;
      int p3row = (b * 48 + nidx[bij]) * 20 + knb;
      float mk = mask[p3row];
      #pragma unroll
      for (int nf = 0; nf < 4; ++nf) {
        float g = acc[mf][nf][r] * d3 + rg[nf];
        float e = acc[mf][nf + 4][r] * d3 + re[nf];
        float val = (1.f / (1.f + expf(-g))) * tanhf(e) * mk;
        atomicAdd(&tsum[(size_t)bij * 64 + nf * 16 + l15], val);
      }
    }
  }
}

__global__ __launch_bounds__(256) void k_bnstats(const float* __restrict__ x, float* __restrict__ mout,
                                                 float* __restrict__ vout) {
  __shared__ float ss[512];
  int c = blockIdx.x, t = threadIdx.x;
  float s = 0.f, q = 0.f;
  for (int r = t; r < R2; r += 256) { float v = x[(size_t)r * 64 + c]; s += v; q += v * v; }
  ss[t] = s; ss[256 + t] = q;
  __syncthreads();
  for (int st = 128; st > 0; st >>= 1) {
    if (t < st) { ss[t] += ss[t + st]; ss[256 + t] += ss[256 + t + st]; }
    __syncthreads();
  }
  if (t == 0) { float m = ss[0] / (float)R2; mout[c] = m; vout[c] = ss[256] / (float)R2 - m * m; }
}

__global__ __launch_bounds__(256) void k_final(const float* __restrict__ edge, const float* __restrict__ two,
                                               const float* __restrict__ tsum, const float* __restrict__ bn,
                                               const float* __restrict__ g2, const float* __restrict__ b2,
                                               const float* __restrict__ g3, const float* __restrict__ b3,
                                               float* __restrict__ out) {
  int idx = blockIdx.x * 256 + threadIdx.x;
  if (idx >= R2 * 64) return;
  int c = idx & 63;
  float t2 = (two[idx] - bn[c]) / sqrtf(bn[64 + c] + 1e-5f) * g2[c] + b2[c];
  float t3 = (tsum[idx] - bn[128 + c]) / sqrtf(bn[192 + c] + 1e-5f) * g3[c] + b3[c];
  out[idx] = fmaxf(0.f, edge[idx] + t2 + t3);
}

// ---------------- host launcher ----------------
extern "C" void kernel_launch(void* const* d_in, const int* in_sizes, int n_in,
                              void* d_out, int out_size, void* d_ws, size_t ws_size,
                              hipStream_t stream) {
  (void)in_sizes; (void)n_in; (void)out_size; (void)ws_size;
  const float* node   = (const float*)d_in[0];
  const float* edge   = (const float*)d_in[1];
  const float* mask   = (const float*)d_in[2];
  const float* c_two  = (const float*)d_in[3];
  const float* c_two2 = (const float*)d_in[4];
  const float* c_three  = (const float*)d_in[5];
  const float* c_three2 = (const float*)d_in[6];
  const float* bn2g = (const float*)d_in[7];
  const float* bn2b = (const float*)d_in[8];
  const float* bn3g = (const float*)d_in[9];
  const float* bn3b = (const float*)d_in[10];
  const int*   nidx = (const int*)d_in[11];
  float* ws = (float*)d_ws;
  unsigned* slots = (unsigned*)(ws + OFF_SLOT);
  float* out = (float*)d_out;
  short* B2AH = (short*)(ws + OFF_B2AH); short* B2AL = (short*)(ws + OFF_B2AL);
  short* B2BH = (short*)(ws + OFF_B2BH); short* B2BL = (short*)(ws + OFF_B2BL);
  short* B3AH = (short*)(ws + OFF_B3AH); short* B3AL = (short*)(ws + OFF_B3AL);
  short* B3BH = (short*)(ws + OFF_B3BH); short* B3BL = (short*)(ws + OFF_B3BL);
  unsigned char* Q2A = (unsigned char*)(ws + OFF_Q2A);
  unsigned char* Q2B = (unsigned char*)(ws + OFF_Q2B);
  unsigned char* QND = (unsigned char*)(ws + OFF_QND);
  unsigned char* QC2 = (unsigned char*)(ws + OFF_QC2);
  unsigned char* QED = (unsigned char*)(ws + OFF_QED);
  unsigned char* QNK = (unsigned char*)(ws + OFF_QNK);

  k_init<<<960, 256, 0, stream>>>(ws + OFF_TSUM, slots);

  k_gen_wexp<<<(8 * 65536 + 255) / 256, 256, 0, stream>>>(c_two,   512, 128, 0u, B2AH, B2AL, ws + OFF_W72A);
  k_gen_wexp<<<(8 * 65536 + 255) / 256, 256, 0, stream>>>(c_two2,  128, 512, 1u, B2BH, B2BL, ws + OFF_W72B);
  k_gen_wexp<<<(8 * 204800 + 255) / 256, 256, 0, stream>>>(c_three, 640, 320, 2u, B3AH, B3AL, ws + OFF_W73A);
  k_gen_wexp<<<(8 * 81920 + 255) / 256, 256, 0, stream>>>(c_three2, 128, 640, 3u, B3BH, B3BL, ws + OFF_W73B);

  k_rowsum<<<2, 256, 0, stream>>>(ws + OFF_W72A, ws + OFF_RS2A, 512, 128);
  k_rowsum<<<1, 256, 0, stream>>>(ws + OFF_W72B, ws + OFF_RS2B, 128, 512);
  k_rowsum<<<3, 256, 0, stream>>>(ws + OFF_W73A, ws + OFF_RS3A, 640, 320);
  k_rowsum<<<1, 256, 0, stream>>>(ws + OFF_W73B, ws + OFF_RS3B, 128, 640);

  // two-body
  k_build_c2<<<1920, 256, 0, stream>>>(node, mask, nidx, ws + OFF_C2IN, slots + 0);
  k_quant<<<1920, 256, 0, stream>>>(ws + OFF_C2IN, 128, 0, 3840, 128, slots + 0, Q2A);
  k_mfma_gemm<<<dim3(4, 30), 256, 0, stream>>>(Q2A, 128, B2AH, B2AL, 1024, 0, 3840, 512, 128, ws + OFF_Z1, 0);
  k_act1<<<7680, 256, 0, stream>>>(ws + OFF_Z1, ws + OFF_RS2A, slots + 0, ws + OFF_C2B, slots + 2);
  k_quant<<<7680, 256, 0, stream>>>(ws + OFF_C2B, 512, 0, 3840, 512, slots + 2, Q2B);
  k_mfma_gemm<<<dim3(1, 30), 256, 0, stream>>>(Q2B, 512, B2BH, B2BL, 4096, 0, 3840, 128, 512, ws + OFF_Z2, 0);
  k_act2<<<960, 256, 0, stream>>>(ws + OFF_Z2, ws + OFF_RS2B, slots + 2, ws + OFF_TWO);

  // three-body min/max (piecewise over materialized c3) + piece quantization
  k_build_nk<<<960, 256, 0, stream>>>(node, nidx, ws + OFF_NK);
  k_minmax_flat<<<48, 256, 0, stream>>>(node, B_ * AT * 64, slots + 4);
  k_minmax_flat<<<960, 256, 0, stream>>>(edge, R2 * 64, slots + 4);
  k_minmax_half<<<960, 256, 0, stream>>>(ws + OFF_C2IN, slots + 4);
  k_minmax_ref3<<<3840, 256, 0, stream>>>(ws + OFF_NK, edge, nidx, slots + 4);

  k_quant<<<48, 256, 0, stream>>>(node, 64, 0, 192, 64, slots + 4, QND);
  k_quant<<<960, 256, 0, stream>>>(ws + OFF_C2IN, 128, 64, 3840, 64, slots + 4, QC2);
  k_quant<<<960, 256, 0, stream>>>(edge, 64, 0, 3840, 64, slots + 4, QED);
  k_quant<<<960, 256, 0, stream>>>(ws + OFF_NK, 64, 0, 3840, 64, slots + 4, QNK);

  // P-piece GEMMs (kp0 = weight-col-offset * 8)
  k_mfma_gemm<<<dim3(5, 2), 256, 0, stream>>>(QND, 64, B3AH, B3AL, 2560, 0,    192,  640, 64, ws + OFF_P1, 0);
  k_mfma_gemm<<<dim3(5, 30), 256, 0, stream>>>(QC2, 64, B3AH, B3AL, 2560, 512,  3840, 640, 64, ws + OFF_P2, 0);
  k_mfma_gemm<<<dim3(5, 30), 256, 0, stream>>>(QED, 64, B3AH, B3AL, 2560, 1536, 3840, 640, 64, ws + OFF_P2, 1);
  k_mfma_gemm<<<dim3(5, 30), 256, 0, stream>>>(QNK, 64, B3AH, B3AL, 2560, 1024, 3840, 640, 64, ws + OFF_P3, 0);
  k_mfma_gemm<<<dim3(5, 30), 256, 0, stream>>>(QED, 64, B3AH, B3AL, 2560, 2048, 3840, 640, 64, ws + OFF_P3, 1);

  k_minmax_c3b<<<4096, 256, 0, stream>>>(ws + OFF_P1, ws + OFF_P2, ws + OFF_P3, ws + OFF_RS3A,
                                         nidx, slots + 4, slots + 6);
  k_mfma_l3b<<<600, 256, 0, stream>>>(ws + OFF_P1, ws + OFF_P2, ws + OFF_P3, ws + OFF_RS3A, ws + OFF_RS3B,
                                      B3BH, B3BL, nidx, mask, slots + 4, slots + 6, ws + OFF_TSUM);

  k_bnstats<<<64, 256, 0, stream>>>(ws + OFF_TWO, ws + OFF_BN + 0, ws + OFF_BN + 64);
  k_bnstats<<<64, 256, 0, stream>>>(ws + OFF_TSUM, ws + OFF_BN + 128, ws + OFF_BN + 192);
  k_final<<<960, 256, 0, stream>>>(edge, ws + OFF_TWO, ws + OFF_TSUM, ws + OFF_BN,
                                   bn2g, bn2b, bn3g, bn3b, out);
}

// Round 3
// 1800.358 us; speedup vs baseline: 15.8353x; 1.6680x over previous
//
#include <hip/hip_runtime.h>
#include <cstdint>
#include <cstddef>

#define DEVI __device__ __forceinline__

typedef __attribute__((ext_vector_type(8))) short s8v;   // 8 bf16 bit patterns
typedef __attribute__((ext_vector_type(4))) float f4v;

static constexpr int B_ = 4, AT = 48, NBRS = 20;
static constexpr int R2 = B_ * AT * NBRS;   // 3840 (b,i,j) rows
static constexpr int M4 = R2 * NBRS;        // 76800 (b,i,j,k) rows

// ---------------- workspace layout (float offsets) ----------------
static constexpr size_t OFF_B2AH = 0;                         // 512x1024 sh
static constexpr size_t OFF_B2AL = OFF_B2AH + 262144;
static constexpr size_t OFF_B2BH = OFF_B2AL + 262144;         // 128x4096 sh
static constexpr size_t OFF_B2BL = OFF_B2BH + 262144;
static constexpr size_t OFF_B3AH = OFF_B2BL + 262144;         // 640x2560 sh (col-permuted)
static constexpr size_t OFF_B3AL = OFF_B3AH + 819200;
static constexpr size_t OFF_B3BH = OFF_B3AL + 819200;         // 128x5120 sh
static constexpr size_t OFF_B3BL = OFF_B3BH + 327680;
static constexpr size_t OFF_W72A = OFF_B3BL + 327680;         // 512x128 f
static constexpr size_t OFF_W72B = OFF_W72A + 65536;          // 128x512 f
static constexpr size_t OFF_W73A = OFF_W72B + 65536;          // 640x320 f
static constexpr size_t OFF_W73B = OFF_W73A + 204800;         // 128x640 f
static constexpr size_t OFF_RS2A = OFF_W73B + 81920;          // 512
static constexpr size_t OFF_RS2B = OFF_RS2A + 512;            // 128
static constexpr size_t OFF_RS3A = OFF_RS2B + 128;            // 640
static constexpr size_t OFF_RS3B = OFF_RS3A + 640;            // 128
static constexpr size_t OFF_SLOT = OFF_RS3B + 128;            // 16 (8 u32 used)
static constexpr size_t OFF_BN   = OFF_SLOT + 16;             // 256
static constexpr size_t OFF_C2IN = OFF_BN + 256;              // 3840x128
static constexpr size_t OFF_Z1   = OFF_C2IN + (size_t)R2 * 128;
static constexpr size_t OFF_C2B  = OFF_Z1 + (size_t)R2 * 512;
static constexpr size_t OFF_Z2   = OFF_C2B + (size_t)R2 * 512;
static constexpr size_t OFF_TWO  = OFF_Z2 + (size_t)R2 * 128;
static constexpr size_t OFF_NK   = OFF_TWO + (size_t)R2 * 64;
static constexpr size_t OFF_P1   = OFF_NK + (size_t)R2 * 64;   // 192x640
static constexpr size_t OFF_P2   = OFF_P1 + (size_t)192 * 640; // 3840x640 (P1 folded in)
static constexpr size_t OFF_P3   = OFF_P2 + (size_t)R2 * 640;
static constexpr size_t OFF_TSUM = OFF_P3 + (size_t)R2 * 640;
static constexpr size_t OFF_Q2A  = OFF_TSUM + (size_t)R2 * 64; // byte buffers (float-sized slots)
static constexpr size_t OFF_Q2B  = OFF_Q2A + 122880;
static constexpr size_t OFF_QND  = OFF_Q2B + 491520;
static constexpr size_t OFF_QP2  = OFF_QND + 3072;             // 3840x128 bytes
static constexpr size_t OFF_QP3  = OFF_QP2 + 122880;           // 3840x128 bytes

// ---------------- threefry-2x32 (JAX-compatible, verified) ----------------
DEVI void tf2x32(unsigned k0, unsigned k1, unsigned x0, unsigned x1,
                 unsigned& o0, unsigned& o1) {
  unsigned ks0 = k0, ks1 = k1, ks2 = k0 ^ k1 ^ 0x1BD11BDAu;
  x0 += ks0; x1 += ks1;
  const unsigned rotA[4] = {13u, 15u, 26u, 6u};
  const unsigned rotB[4] = {17u, 29u, 16u, 24u};
  unsigned ks[3] = {ks0, ks1, ks2};
  #pragma unroll
  for (int i = 0; i < 5; ++i) {
    const unsigned* rot = (i & 1) ? rotB : rotA;
    #pragma unroll
    for (int r = 0; r < 4; ++r) {
      x0 += x1;
      x1 = (x1 << rot[r]) | (x1 >> (32u - rot[r]));
      x1 ^= x0;
    }
    x0 += ks[(i + 1) % 3];
    x1 += ks[(i + 2) % 3] + (unsigned)(i + 1);
  }
  o0 = x0; o1 = x1;
}

DEVI float erfinv_xla(float x) {
  float w = -log1pf(-x * x);
  float p;
  if (w < 5.f) {
    w -= 2.5f;
    p = 2.81022636e-08f;
    p = fmaf(p, w, 3.43273939e-07f);
    p = fmaf(p, w, -3.5233877e-06f);
    p = fmaf(p, w, -4.39150654e-06f);
    p = fmaf(p, w, 0.00021858087f);
    p = fmaf(p, w, -0.00125372503f);
    p = fmaf(p, w, -0.00417768164f);
    p = fmaf(p, w, 0.246640727f);
    p = fmaf(p, w, 1.50140941f);
  } else {
    w = sqrtf(w) - 3.f;
    p = -0.000200214257f;
    p = fmaf(p, w, 0.000100950558f);
    p = fmaf(p, w, 0.00134934322f);
    p = fmaf(p, w, -0.00367342844f);
    p = fmaf(p, w, 0.00573950773f);
    p = fmaf(p, w, -0.0076224613f);
    p = fmaf(p, w, 0.00943887047f);
    p = fmaf(p, w, 1.00167406f);
    p = fmaf(p, w, 2.83297682f);
  }
  return p * x;
}

DEVI float normal_from_bits(unsigned bits) {
  unsigned fb = (bits >> 9) | 0x3F800000u;
  float f = __uint_as_float(fb) - 1.0f;
  const float lo = -0.99999994f;
  float u = f * (1.0f - lo) + lo;
  u = fmaxf(lo, u);
  return 1.41421356237f * erfinv_xla(u);
}

DEVI unsigned f2o(float f) { unsigned u = __float_as_uint(f); return (u & 0x80000000u) ? ~u : (u | 0x80000000u); }
DEVI float o2f(unsigned u) { return (u & 0x80000000u) ? __uint_as_float(u & 0x7FFFFFFFu) : __uint_as_float(~u); }

DEVI unsigned short f2bf(float x) {  // RNE f32 -> bf16
  unsigned u = __float_as_uint(x);
  return (unsigned short)((u + 0x7FFFu + ((u >> 16) & 1u)) >> 16);
}
DEVI float bf2f(unsigned short h) { return __uint_as_float((unsigned)h << 16); }

DEVI void blockMinMax(float lmn, float lmx, float* smem, unsigned* slot) {
  float* smn = smem; float* smx = smem + 256;
  int t = threadIdx.x;
  smn[t] = lmn; smx[t] = lmx;
  __syncthreads();
  for (int s = 128; s > 0; s >>= 1) {
    if (t < s) { smn[t] = fminf(smn[t], smn[t + s]); smx[t] = fmaxf(smx[t], smx[t + s]); }
    __syncthreads();
  }
  if (t == 0) { atomicMin(slot + 0, f2o(smn[0])); atomicMax(slot + 1, f2o(smx[0])); }
}

DEVI s8v expand_bits(unsigned b) {
  s8v f;
  #pragma unroll
  for (int j = 0; j < 8; ++j) f[j] = (short)(((b >> j) & 1u) ? 0x3F80 : 0);
  return f;
}

// ---------------- kernels ----------------
__global__ __launch_bounds__(256) void k_init(float* __restrict__ z1, float* __restrict__ z2,
                                              float* __restrict__ tsum, unsigned* __restrict__ slots) {
  int i = blockIdx.x * 256 + threadIdx.x;
  if (i < R2 * 512) z1[i] = 0.f;
  if (i < R2 * 128) z2[i] = 0.f;
  if (i < R2 * 64) tsum[i] = 0.f;
  if (i < 4) { slots[2 * i] = f2o(3.402823466e38f); slots[2 * i + 1] = f2o(-3.402823466e38f); }
}

// Expanded noisy weights: Bhi/Blo[n][pk*8+bit] = bf16split(2^bit * (W + N*|W|*0.1)); Wn7 = bit-7 noisy W
// perm: layer-3A column permutation [node_i | node_j, edge_ij | node_k, edge_jk]
__global__ __launch_bounds__(256) void k_gen_wexp(const float* __restrict__ W, int N, int K, unsigned layer,
                                                  short* __restrict__ Bhi, short* __restrict__ Blo,
                                                  float* __restrict__ Wn7, int perm) {
  int t = blockIdx.x * 256 + threadIdx.x;
  int n_elem = N * K;
  if (t >= n_elem * 8) return;
  int bit = t / n_elem;
  int e = t - bit * n_elem;
  unsigned kl0, kl1, kb0, kb1, r0, r1;
  tf2x32(0u, 42u, 0u, layer, kl0, kl1);
  tf2x32(kl0, kl1, 0u, (unsigned)bit, kb0, kb1);
  tf2x32(kb0, kb1, 0u, (unsigned)e, r0, r1);
  float w = W[e];
  float wn = w + normal_from_bits(r0 ^ r1) * fabsf(w) * 0.1f;
  float sv = ldexpf(wn, bit);
  unsigned short hi = f2bf(sv);
  unsigned short lo = f2bf(sv - bf2f(hi));
  int n = e / K, k = e - n * K;
  int pk = k;
  if (perm) {
    if (k >= 128 && k < 192) pk = k + 64;         // node_k -> pos 192..256
    else if (k >= 192 && k < 256) pk = k - 64;    // edge_ij -> pos 128..192
  }
  size_t off = (size_t)n * ((size_t)K * 8) + (size_t)pk * 8 + bit;
  Bhi[off] = (short)hi; Blo[off] = (short)lo;
  if (bit == 7) Wn7[e] = wn;
}

__global__ __launch_bounds__(256) void k_rowsum(const float* __restrict__ Wn7, float* __restrict__ rs,
                                                int rows, int cols) {
  int o = blockIdx.x * 256 + threadIdx.x;
  if (o >= rows) return;
  const float* p = Wn7 + (size_t)o * cols;
  float s = 0.f;
  for (int j = 0; j < cols; ++j) s += p[j];
  rs[o] = s;
}

__global__ __launch_bounds__(256) void k_build_c2(const float* __restrict__ node, const float* __restrict__ mask,
                                                  const int* __restrict__ nidx, float* __restrict__ c2in,
                                                  unsigned* __restrict__ slot) {
  __shared__ float sred[512];
  int idx = blockIdx.x * 256 + threadIdx.x;
  float lmn = 3.4e38f, lmx = -3.4e38f;
  if (idx < R2 * 128) {
    int row = idx >> 7, c = idx & 127;
    float v;
    if (c < 64) v = node[(size_t)(row / 20) * 64 + c];
    else {
      int b = row / 960;
      v = node[(size_t)(b * 48 + nidx[row]) * 64 + (c - 64)] * mask[row];
    }
    c2in[idx] = v; lmn = v; lmx = v;
  }
  blockMinMax(lmn, lmx, sred, slot);
}

__global__ __launch_bounds__(256) void k_build_nk(const float* __restrict__ node, const int* __restrict__ nidx,
                                                  float* __restrict__ NK) {
  int idx = blockIdx.x * 256 + threadIdx.x;
  if (idx >= R2 * 64) return;
  int row = idx >> 6, c = idx & 63;
  int b = row / 960;
  NK[idx] = node[(size_t)(b * 48 + nidx[row]) * 64 + c];
}

__global__ __launch_bounds__(256) void k_minmax_flat(const float* __restrict__ x, int n, unsigned* __restrict__ slot) {
  __shared__ float sred[512];
  float lmn = 3.4e38f, lmx = -3.4e38f;
  for (int idx = blockIdx.x * 256 + threadIdx.x; idx < n; idx += gridDim.x * 256) {
    float v = x[idx]; lmn = fminf(lmn, v); lmx = fmaxf(lmx, v);
  }
  blockMinMax(lmn, lmx, sred, slot);
}

__global__ __launch_bounds__(256) void k_minmax_half(const float* __restrict__ c2in, unsigned* __restrict__ slot) {
  __shared__ float sred[512];
  int idx = blockIdx.x * 256 + threadIdx.x;
  float lmn = 3.4e38f, lmx = -3.4e38f;
  if (idx < R2 * 64) {
    int r = idx >> 6, c = idx & 63;
    float v = c2in[(size_t)r * 128 + 64 + c];
    lmn = v; lmx = v;
  }
  blockMinMax(lmn, lmx, sred, slot);
}

__global__ __launch_bounds__(256) void k_minmax_ref3(const float* __restrict__ NK, const float* __restrict__ edge,
                                                     const int* __restrict__ nidx, unsigned* __restrict__ slot) {
  __shared__ float sred[512];
  int bij = blockIdx.x;
  int b = bij / 960;
  int jp = nidx[bij];
  size_t base = (size_t)((b * 48 + jp) * 20) * 64;
  float lmn = 3.4e38f, lmx = -3.4e38f;
  for (int t = threadIdx.x; t < 20 * 64; t += 256) {
    float v1 = NK[base + t];
    float v2 = edge[base + t];
    lmn = fminf(lmn, fminf(v1, v2));
    lmx = fmaxf(lmx, fmaxf(v1, v2));
  }
  blockMinMax(lmn, lmx, sred, slot);
}

__global__ __launch_bounds__(256) void k_quant(const float* __restrict__ X, int ld, int col0,
                                               int rows, int cols, const unsigned* __restrict__ slot,
                                               unsigned char* __restrict__ Q, int qld, int qc0) {
  int idx = blockIdx.x * 256 + threadIdx.x;
  if (idx >= rows * cols) return;
  int r = idx / cols, c = idx - r * cols;
  const float mn = o2f(slot[0]), mx = o2f(slot[1]);
  float invd = 255.f / (mx - mn);
  Q[(size_t)r * qld + qc0 + c] = (unsigned char)((X[(size_t)r * ld + col0 + c] - mn) * invd);
}

// Generic MFMA bit-serial GEMM; split-K via gridDim.z (accflag: 0=store, 1=+=, 3=atomicAdd)
// block 128x128, 4 waves 2x2, wave = 64 rows x 64 cols
__global__ __launch_bounds__(256) void k_mfma_gemm(
    const unsigned char* __restrict__ Q, int ldq,
    const short* __restrict__ Bhi, const short* __restrict__ Blo, int ldb, int kp0,
    int M, int Nfull, int KB, float* __restrict__ Z, int accflag) {
  const int tid = threadIdx.x;
  const int lane = tid & 63, wave = tid >> 6;
  const int wr = wave >> 1, wc = wave & 1;
  const int l15 = lane & 15, l4 = lane >> 4;
  const int mbase = blockIdx.y * 128 + wr * 64;
  const int nbase = blockIdx.x * 128 + wc * 64;
  const int kq0 = blockIdx.z * KB;
  f4v acc[4][4];
  #pragma unroll
  for (int a = 0; a < 4; ++a)
    #pragma unroll
    for (int b = 0; b < 4; ++b) acc[a][b] = f4v{0.f, 0.f, 0.f, 0.f};
  for (int ks = 0; ks < KB; ks += 4) {
    s8v af[4];
    #pragma unroll
    for (int mf = 0; mf < 4; ++mf) {
      int row = mbase + mf * 16 + l15; if (row >= M) row = M - 1;
      unsigned w = *(const unsigned*)(Q + (size_t)row * ldq + kq0 + ks);
      af[mf] = expand_bits((w >> (l4 * 8)) & 255u);
    }
    #pragma unroll
    for (int nf = 0; nf < 4; ++nf) {
      size_t boff = (size_t)(nbase + nf * 16 + l15) * ldb + kp0 + (kq0 + ks) * 8 + l4 * 8;
      s8v bh = *(const s8v*)(Bhi + boff);
      s8v bl = *(const s8v*)(Blo + boff);
      #pragma unroll
      for (int mf = 0; mf < 4; ++mf) {
        acc[mf][nf] = __builtin_amdgcn_mfma_f32_16x16x32_bf16(af[mf], bh, acc[mf][nf], 0, 0, 0);
        acc[mf][nf] = __builtin_amdgcn_mfma_f32_16x16x32_bf16(af[mf], bl, acc[mf][nf], 0, 0, 0);
      }
    }
  }
  #pragma unroll
  for (int mf = 0; mf < 4; ++mf) {
    #pragma unroll
    for (int r = 0; r < 4; ++r) {
      int m = mbase + mf * 16 + l4 * 4 + r;
      if (m >= M) continue;
      float* zp = Z + (size_t)m * Nfull + nbase;
      #pragma unroll
      for (int nf = 0; nf < 4; ++nf) {
        int n = nf * 16 + l15;
        if (accflag == 0) zp[n] = acc[mf][nf][r];
        else if (accflag == 1) zp[n] += acc[mf][nf][r];
        else atomicAdd(zp + n, acc[mf][nf][r]);
      }
    }
  }
}

// Merged P2/P3 GEMM (K'=1024 each, permuted B3A); P2 half adds P1 row in epilogue
__global__ __launch_bounds__(256) void k_mfma_p23(
    const unsigned char* __restrict__ Q2, const unsigned char* __restrict__ Q3,
    const short* __restrict__ Bhi, const short* __restrict__ Blo,
    const float* __restrict__ P1, float* __restrict__ P2, float* __restrict__ P3) {
  const int half = blockIdx.y >= 30;
  const int by = blockIdx.y - half * 30;
  const unsigned char* Q = half ? Q3 : Q2;
  float* Z = half ? P3 : P2;
  const int kp0 = half ? 1536 : 512;
  const int tid = threadIdx.x;
  const int lane = tid & 63, wave = tid >> 6;
  const int wr = wave >> 1, wc = wave & 1;
  const int l15 = lane & 15, l4 = lane >> 4;
  const int mbase = by * 128 + wr * 64;
  const int nbase = blockIdx.x * 128 + wc * 64;
  f4v acc[4][4];
  #pragma unroll
  for (int a = 0; a < 4; ++a)
    #pragma unroll
    for (int b = 0; b < 4; ++b) acc[a][b] = f4v{0.f, 0.f, 0.f, 0.f};
  for (int ks = 0; ks < 128; ks += 4) {
    s8v af[4];
    #pragma unroll
    for (int mf = 0; mf < 4; ++mf) {
      unsigned w = *(const unsigned*)(Q + (size_t)(mbase + mf * 16 + l15) * 128 + ks);
      af[mf] = expand_bits((w >> (l4 * 8)) & 255u);
    }
    #pragma unroll
    for (int nf = 0; nf < 4; ++nf) {
      size_t boff = (size_t)(nbase + nf * 16 + l15) * 2560 + kp0 + ks * 8 + l4 * 8;
      s8v bh = *(const s8v*)(Bhi + boff);
      s8v bl = *(const s8v*)(Blo + boff);
      #pragma unroll
      for (int mf = 0; mf < 4; ++mf) {
        acc[mf][nf] = __builtin_amdgcn_mfma_f32_16x16x32_bf16(af[mf], bh, acc[mf][nf], 0, 0, 0);
        acc[mf][nf] = __builtin_amdgcn_mfma_f32_16x16x32_bf16(af[mf], bl, acc[mf][nf], 0, 0, 0);
      }
    }
  }
  #pragma unroll
  for (int mf = 0; mf < 4; ++mf) {
    #pragma unroll
    for (int r = 0; r < 4; ++r) {
      int m = mbase + mf * 16 + l4 * 4 + r;
      float* zp = Z + (size_t)m * 640 + nbase;
      const float* ap = P1 + (size_t)(m / 20) * 640 + nbase;
      #pragma unroll
      for (int nf = 0; nf < 4; ++nf) {
        int n = nf * 16 + l15;
        zp[n] = half ? acc[mf][nf][r] : (acc[mf][nf][r] + ap[n]);
      }
    }
  }
}

__global__ __launch_bounds__(256) void k_act1(const float* __restrict__ z1, const float* __restrict__ rs,
                                              const unsigned* __restrict__ slot0, float* __restrict__ c2b,
                                              unsigned* __restrict__ slot1) {
  __shared__ float sred[512];
  const float mn = o2f(slot0[0]), mx = o2f(slot0[1]);
  int idx = blockIdx.x * 256 + threadIdx.x;
  float lmn = 3.4e38f, lmx = -3.4e38f;
  if (idx < R2 * 512) {
    int o = idx & 511;
    float v = fmaxf(0.f, z1[idx] * (1.f / 255.f) * (mx - mn) + mn * rs[o]);
    c2b[idx] = v; lmn = v; lmx = v;
  }
  blockMinMax(lmn, lmx, sred, slot1);
}

__global__ __launch_bounds__(256) void k_act2(const float* __restrict__ z2, const float* __restrict__ rs,
                                              const unsigned* __restrict__ slot, float* __restrict__ two) {
  int idx = blockIdx.x * 256 + threadIdx.x;
  if (idx >= R2 * 64) return;
  const float mn = o2f(slot[0]), mx = o2f(slot[1]);
  int row = idx >> 6, c = idx & 63;
  float d = (mx - mn) * (1.f / 255.f);
  float g = z2[(size_t)row * 128 + c] * d + mn * rs[c];
  float e = z2[(size_t)row * 128 + 64 + c] * d + mn * rs[64 + c];
  two[idx] = (1.f / (1.f + expf(-g))) * tanhf(e);
}

// min/max of relu(requant(z3)) — block per (b,i,j): P12 row in LDS + 20 contiguous P3 rows
__global__ __launch_bounds__(256) void k_minmax3(
    const float* __restrict__ P12, const float* __restrict__ P3,
    const float* __restrict__ rs3a, const int* __restrict__ nidx,
    const unsigned* __restrict__ slot2, unsigned* __restrict__ slot3) {
  __shared__ float p12s[640];
  __shared__ float bias[640];
  __shared__ float sred[512];
  const int bij = blockIdx.x;
  const int b = bij / 960;
  const int jp = nidx[bij];
  const size_t p3b = (size_t)((b * 48 + jp) * 20) * 640;
  const float mn2 = o2f(slot2[0]), mx2 = o2f(slot2[1]);
  const float sc2 = (mx2 - mn2) * (1.f / 255.f);
  for (int k = threadIdx.x; k < 640; k += 256) {
    p12s[k] = P12[(size_t)bij * 640 + k];
    bias[k] = mn2 * rs3a[k];
  }
  __syncthreads();
  float lmn = 3.4e38f, lmx = -3.4e38f;
  for (int t = threadIdx.x; t < 20 * 640; t += 256) {
    int knb = t / 640, k = t - knb * 640;
    float v = fmaxf(0.f, (p12s[k] + P3[p3b + t]) * sc2 + bias[k]);
    lmn = fminf(lmn, v); lmx = fmaxf(lmx, v);
  }
  blockMinMax(lmn, lmx, sred, slot3);
}

// Fused 3-body layer 2: 64-row blocks (3/CU), 4 waves 2m x 2n (g/e pairs in-wave),
// LDS A-tile build from P12+P3, MFMA K'=5120, epilogue sigmoid*tanh*mask + atomic k-sum
__global__ __launch_bounds__(256) void k_mfma_l3b(
    const float* __restrict__ P12, const float* __restrict__ P3,
    const float* __restrict__ rs3a, const float* __restrict__ rs3b,
    const short* __restrict__ Bhi, const short* __restrict__ Blo,
    const int* __restrict__ nidx, const float* __restrict__ mask,
    const unsigned* __restrict__ slotA, const unsigned* __restrict__ slotB,
    float* __restrict__ tsum) {
  __shared__ unsigned char qt[64 * 648];
  const int tid = threadIdx.x;
  const int s0 = blockIdx.x * 64;
  const float mn2 = o2f(slotA[0]), mx2 = o2f(slotA[1]);
  const float mn3 = o2f(slotB[0]), mx3 = o2f(slotB[1]);
  const float sc2 = (mx2 - mn2) * (1.f / 255.f);
  const float invd3 = 255.f / (mx3 - mn3);
  {
    int r = tid >> 2, kq = (tid & 3) * 160;
    int s = s0 + r;
    int bij = s / 20, knb = s - bij * 20, b = bij / 960;
    int p3row = (b * 48 + nidx[bij]) * 20 + knb;
    const float* pa = P12 + (size_t)bij * 640;
    const float* pb = P3 + (size_t)p3row * 640;
    for (int k = kq; k < kq + 160; k += 4) {
      float4 va = *(const float4*)(pa + k);
      float4 vb = *(const float4*)(pb + k);
      unsigned pk = 0;
      float v0 = fmaxf(0.f, (va.x + vb.x) * sc2 + mn2 * rs3a[k + 0]);
      float v1 = fmaxf(0.f, (va.y + vb.y) * sc2 + mn2 * rs3a[k + 1]);
      float v2 = fmaxf(0.f, (va.z + vb.z) * sc2 + mn2 * rs3a[k + 2]);
      float v3 = fmaxf(0.f, (va.w + vb.w) * sc2 + mn2 * rs3a[k + 3]);
      pk = (unsigned)((v0 - mn3) * invd3) | ((unsigned)((v1 - mn3) * invd3) << 8)
         | ((unsigned)((v2 - mn3) * invd3) << 16) | ((unsigned)((v3 - mn3) * invd3) << 24);
      *(unsigned*)(&qt[(size_t)r * 648 + k]) = pk;
    }
  }
  __syncthreads();
  const int lane = tid & 63, wave = tid >> 6;
  const int wm = wave >> 1, wn = wave & 1;
  const int l15 = lane & 15, l4 = lane >> 4;
  const int nfl[4] = {2 * wn, 2 * wn + 1, 2 * wn + 4, 2 * wn + 5};
  f4v acc[2][4];
  #pragma unroll
  for (int a = 0; a < 2; ++a)
    #pragma unroll
    for (int b = 0; b < 4; ++b) acc[a][b] = f4v{0.f, 0.f, 0.f, 0.f};
  for (int ks = 0; ks < 640; ks += 4) {
    s8v af[2];
    #pragma unroll
    for (int mf = 0; mf < 2; ++mf) {
      unsigned w = *(const unsigned*)(&qt[(size_t)(wm * 32 + mf * 16 + l15) * 648 + ks]);
      af[mf] = expand_bits((w >> (l4 * 8)) & 255u);
    }
    #pragma unroll
    for (int j = 0; j < 4; ++j) {
      size_t boff = (size_t)(nfl[j] * 16 + l15) * 5120 + ks * 8 + l4 * 8;
      s8v bh = *(const s8v*)(Bhi + boff);
      s8v bl = *(const s8v*)(Blo + boff);
      #pragma unroll
      for (int mf = 0; mf < 2; ++mf) {
        acc[mf][j] = __builtin_amdgcn_mfma_f32_16x16x32_bf16(af[mf], bh, acc[mf][j], 0, 0, 0);
        acc[mf][j] = __builtin_amdgcn_mfma_f32_16x16x32_bf16(af[mf], bl, acc[mf][j], 0, 0, 0);
      }
    }
  }
  const float d3 = (mx3 - mn3) * (1.f / 255.f);
  float rg[2], re[2];
  #pragma unroll
  for (int j = 0; j < 2; ++j) {
    int gcol = (2 * wn + j) * 16 + l15;
    rg[j] = mn3 * rs3b[gcol];
    re[j] = mn3 * rs3b[64 + gcol];
  }
  #pragma unroll
  for (int mf = 0; mf < 2; ++mf) {
    #pragma unroll
    for (int r = 0; r < 4; ++r) {
      int s = s0 + wm * 32 + mf * 16 + l4 * 4 + r;
      int bij = s / 20, knb = s - bij * 20, b = bij / 960;
      int p3row = (b * 48 + nidx[bij]) * 20 + knb;
      float mk = mask[p3row];
      #pragma unroll
      for (int j = 0; j < 2; ++j) {
        float g = acc[mf][j][r] * d3 + rg[j];
        float e = acc[mf][j + 2][r] * d3 + re[j];
        float val = (1.f / (1.f + expf(-g))) * tanhf(e) * mk;
        atomicAdd(&tsum[(size_t)bij * 64 + (2 * wn + j) * 16 + l15], val);
      }
    }
  }
}

__global__ __launch_bounds__(256) void k_bnstats(const float* __restrict__ x, float* __restrict__ mout,
                                                 float* __restrict__ vout) {
  __shared__ float ss[512];
  int c = blockIdx.x, t = threadIdx.x;
  float s = 0.f, q = 0.f;
  for (int r = t; r < R2; r += 256) { float v = x[(size_t)r * 64 + c]; s += v; q += v * v; }
  ss[t] = s; ss[256 + t] = q;
  __syncthreads();
  for (int st = 128; st > 0; st >>= 1) {
    if (t < st) { ss[t] += ss[t + st]; ss[256 + t] += ss[256 + t + st]; }
    __syncthreads();
  }
  if (t == 0) { float m = ss[0] / (float)R2; mout[c] = m; vout[c] = ss[256] / (float)R2 - m * m; }
}

__global__ __launch_bounds__(256) void k_final(const float* __restrict__ edge, const float* __restrict__ two,
                                               const float* __restrict__ tsum, const float* __restrict__ bn,
                                               const float* __restrict__ g2, const float* __restrict__ b2,
                                               const float* __restrict__ g3, const float* __restrict__ b3,
                                               float* __restrict__ out) {
  int idx = blockIdx.x * 256 + threadIdx.x;
  if (idx >= R2 * 64) return;
  int c = idx & 63;
  float t2 = (two[idx] - bn[c]) / sqrtf(bn[64 + c] + 1e-5f) * g2[c] + b2[c];
  float t3 = (tsum[idx] - bn[128 + c]) / sqrtf(bn[192 + c] + 1e-5f) * g3[c] + b3[c];
  out[idx] = fmaxf(0.f, edge[idx] + t2 + t3);
}

// ---------------- host launcher ----------------
extern "C" void kernel_launch(void* const* d_in, const int* in_sizes, int n_in,
                              void* d_out, int out_size, void* d_ws, size_t ws_size,
                              hipStream_t stream) {
  (void)in_sizes; (void)n_in; (void)out_size; (void)ws_size;
  const float* node   = (const float*)d_in[0];
  const float* edge   = (const float*)d_in[1];
  const float* mask   = (const float*)d_in[2];
  const float* c_two  = (const float*)d_in[3];
  const float* c_two2 = (const float*)d_in[4];
  const float* c_three  = (const float*)d_in[5];
  const float* c_three2 = (const float*)d_in[6];
  const float* bn2g = (const float*)d_in[7];
  const float* bn2b = (const float*)d_in[8];
  const float* bn3g = (const float*)d_in[9];
  const float* bn3b = (const float*)d_in[10];
  const int*   nidx = (const int*)d_in[11];
  float* ws = (float*)d_ws;
  unsigned* slots = (unsigned*)(ws + OFF_SLOT);
  float* out = (float*)d_out;
  short* B2AH = (short*)(ws + OFF_B2AH); short* B2AL = (short*)(ws + OFF_B2AL);
  short* B2BH = (short*)(ws + OFF_B2BH); short* B2BL = (short*)(ws + OFF_B2BL);
  short* B3AH = (short*)(ws + OFF_B3AH); short* B3AL = (short*)(ws + OFF_B3AL);
  short* B3BH = (short*)(ws + OFF_B3BH); short* B3BL = (short*)(ws + OFF_B3BL);
  unsigned char* Q2A = (unsigned char*)(ws + OFF_Q2A);
  unsigned char* Q2B = (unsigned char*)(ws + OFF_Q2B);
  unsigned char* QND = (unsigned char*)(ws + OFF_QND);
  unsigned char* QP2 = (unsigned char*)(ws + OFF_QP2);
  unsigned char* QP3 = (unsigned char*)(ws + OFF_QP3);

  k_init<<<7680, 256, 0, stream>>>(ws + OFF_Z1, ws + OFF_Z2, ws + OFF_TSUM, slots);

  k_gen_wexp<<<(8 * 65536 + 255) / 256, 256, 0, stream>>>(c_two,   512, 128, 0u, B2AH, B2AL, ws + OFF_W72A, 0);
  k_gen_wexp<<<(8 * 65536 + 255) / 256, 256, 0, stream>>>(c_two2,  128, 512, 1u, B2BH, B2BL, ws + OFF_W72B, 0);
  k_gen_wexp<<<(8 * 204800 + 255) / 256, 256, 0, stream>>>(c_three, 640, 320, 2u, B3AH, B3AL, ws + OFF_W73A, 1);
  k_gen_wexp<<<(8 * 81920 + 255) / 256, 256, 0, stream>>>(c_three2, 128, 640, 3u, B3BH, B3BL, ws + OFF_W73B, 0);

  k_rowsum<<<2, 256, 0, stream>>>(ws + OFF_W72A, ws + OFF_RS2A, 512, 128);
  k_rowsum<<<1, 256, 0, stream>>>(ws + OFF_W72B, ws + OFF_RS2B, 128, 512);
  k_rowsum<<<3, 256, 0, stream>>>(ws + OFF_W73A, ws + OFF_RS3A, 640, 320);
  k_rowsum<<<1, 256, 0, stream>>>(ws + OFF_W73B, ws + OFF_RS3B, 128, 640);

  // two-body
  k_build_c2<<<1920, 256, 0, stream>>>(node, mask, nidx, ws + OFF_C2IN, slots + 0);
  k_quant<<<1920, 256, 0, stream>>>(ws + OFF_C2IN, 128, 0, 3840, 128, slots + 0, Q2A, 128, 0);
  k_mfma_gemm<<<dim3(4, 30, 2), 256, 0, stream>>>(Q2A, 128, B2AH, B2AL, 1024, 0, 3840, 512, 64, ws + OFF_Z1, 3);
  k_act1<<<7680, 256, 0, stream>>>(ws + OFF_Z1, ws + OFF_RS2A, slots + 0, ws + OFF_C2B, slots + 2);
  k_quant<<<7680, 256, 0, stream>>>(ws + OFF_C2B, 512, 0, 3840, 512, slots + 2, Q2B, 512, 0);
  k_mfma_gemm<<<dim3(1, 30, 4), 256, 0, stream>>>(Q2B, 512, B2BH, B2BL, 4096, 0, 3840, 128, 128, ws + OFF_Z2, 3);
  k_act2<<<960, 256, 0, stream>>>(ws + OFF_Z2, ws + OFF_RS2B, slots + 2, ws + OFF_TWO);

  // three-body: piecewise c3 min/max, piece quantization
  k_build_nk<<<960, 256, 0, stream>>>(node, nidx, ws + OFF_NK);
  k_minmax_flat<<<48, 256, 0, stream>>>(node, B_ * AT * 64, slots + 4);
  k_minmax_flat<<<960, 256, 0, stream>>>(edge, R2 * 64, slots + 4);
  k_minmax_half<<<960, 256, 0, stream>>>(ws + OFF_C2IN, slots + 4);
  k_minmax_ref3<<<3840, 256, 0, stream>>>(ws + OFF_NK, edge, nidx, slots + 4);

  k_quant<<<48, 256, 0, stream>>>(node, 64, 0, 192, 64, slots + 4, QND, 64, 0);
  k_quant<<<960, 256, 0, stream>>>(ws + OFF_C2IN, 128, 64, 3840, 64, slots + 4, QP2, 128, 0);
  k_quant<<<960, 256, 0, stream>>>(edge, 64, 0, 3840, 64, slots + 4, QP2, 128, 64);
  k_quant<<<960, 256, 0, stream>>>(ws + OFF_NK, 64, 0, 3840, 64, slots + 4, QP3, 128, 0);
  k_quant<<<960, 256, 0, stream>>>(edge, 64, 0, 3840, 64, slots + 4, QP3, 128, 64);

  // P1 (node_i, K'=512), then merged P2/P3 (K'=1024 each, P1 folded into P2)
  k_mfma_gemm<<<dim3(5, 2, 1), 256, 0, stream>>>(QND, 64, B3AH, B3AL, 2560, 0, 192, 640, 64, ws + OFF_P1, 0);
  k_mfma_p23<<<dim3(5, 60), 256, 0, stream>>>(QP2, QP3, B3AH, B3AL, ws + OFF_P1, ws + OFF_P2, ws + OFF_P3);

  k_minmax3<<<3840, 256, 0, stream>>>(ws + OFF_P2, ws + OFF_P3, ws + OFF_RS3A, nidx, slots + 4, slots + 6);
  k_mfma_l3b<<<1200, 256, 0, stream>>>(ws + OFF_P2, ws + OFF_P3, ws + OFF_RS3A, ws + OFF_RS3B,
                                       B3BH, B3BL, nidx, mask, slots + 4, slots + 6, ws + OFF_TSUM);

  k_bnstats<<<64, 256, 0, stream>>>(ws + OFF_TWO, ws + OFF_BN + 0, ws + OFF_BN + 64);
  k_bnstats<<<64, 256, 0, stream>>>(ws + OFF_TSUM, ws + OFF_BN + 128, ws + OFF_BN + 192);
  k_final<<<960, 256, 0, stream>>>(edge, ws + OFF_TWO, ws + OFF_TSUM, ws + OFF_BN,
                                   bn2g, bn2b, bn3g, bn3b, out);
}

// Round 4
// 1043.187 us; speedup vs baseline: 27.3290x; 1.7258x over previous
//
#include <hip/hip_runtime.h>
#include <cstdint>
#include <cstddef>

#define DEVI __device__ __forceinline__

typedef __attribute__((ext_vector_type(8))) short s8v;   // 8 bf16 bit patterns
typedef __attribute__((ext_vector_type(4))) float f4v;

static constexpr int B_ = 4, AT = 48, NBRS = 20;
static constexpr int R2 = B_ * AT * NBRS;   // 3840 (b,i,j) rows
static constexpr int M4 = R2 * NBRS;        // 76800 (b,i,j,k) rows

// ---------------- workspace layout (float offsets) ----------------
// fragment-major expanded weights (hi/lo interleaved), sizes in floats = N*K'*2/2
static constexpr size_t OFF_B2A  = 0;                          // 512x128: 524288 f
static constexpr size_t OFF_B2B  = OFF_B2A + 524288;           // 128x512: 524288 f
static constexpr size_t OFF_B3A  = OFF_B2B + 524288;           // 640x320: 1638400 f
static constexpr size_t OFF_B3B  = OFF_B3A + 1638400;          // 128x640: 655360 f
static constexpr size_t OFF_W72A = OFF_B3B + 655360;           // 512x128 f
static constexpr size_t OFF_W72B = OFF_W72A + 65536;           // 128x512 f
static constexpr size_t OFF_W73A = OFF_W72B + 65536;           // 640x320 f
static constexpr size_t OFF_W73B = OFF_W73A + 204800;          // 128x640 f
static constexpr size_t OFF_RS2A = OFF_W73B + 81920;           // 512
static constexpr size_t OFF_RS2B = OFF_RS2A + 512;             // 128
static constexpr size_t OFF_RS3A = OFF_RS2B + 128;             // 640
static constexpr size_t OFF_RS3B = OFF_RS3A + 640;             // 128
static constexpr size_t OFF_SLOT = OFF_RS3B + 128;             // 16
static constexpr size_t OFF_BN   = OFF_SLOT + 16;              // 256
static constexpr size_t OFF_C2IN = OFF_BN + 256;               // 3840x128
static constexpr size_t OFF_Z1   = OFF_C2IN + (size_t)R2 * 128;
static constexpr size_t OFF_C2B  = OFF_Z1 + (size_t)R2 * 512;
static constexpr size_t OFF_Z2   = OFF_C2B + (size_t)R2 * 512;
static constexpr size_t OFF_TWO  = OFF_Z2 + (size_t)R2 * 128;
static constexpr size_t OFF_NK   = OFF_TWO + (size_t)R2 * 64;
static constexpr size_t OFF_P1   = OFF_NK + (size_t)R2 * 64;   // 192x640
static constexpr size_t OFF_P2   = OFF_P1 + (size_t)192 * 640; // 3840x640
static constexpr size_t OFF_P3   = OFF_P2 + (size_t)R2 * 640;
static constexpr size_t OFF_TSUM = OFF_P3 + (size_t)R2 * 640;
static constexpr size_t OFF_Q2A  = OFF_TSUM + (size_t)R2 * 64;
static constexpr size_t OFF_Q2B  = OFF_Q2A + 122880;
static constexpr size_t OFF_QND  = OFF_Q2B + 491520;
static constexpr size_t OFF_QP2  = OFF_QND + 3072;             // 3840x128 bytes
static constexpr size_t OFF_QP3  = OFF_QP2 + 122880;           // 3840x128 bytes

// ---------------- threefry-2x32 (JAX-compatible, verified) ----------------
DEVI void tf2x32(unsigned k0, unsigned k1, unsigned x0, unsigned x1,
                 unsigned& o0, unsigned& o1) {
  unsigned ks0 = k0, ks1 = k1, ks2 = k0 ^ k1 ^ 0x1BD11BDAu;
  x0 += ks0; x1 += ks1;
  const unsigned rotA[4] = {13u, 15u, 26u, 6u};
  const unsigned rotB[4] = {17u, 29u, 16u, 24u};
  unsigned ks[3] = {ks0, ks1, ks2};
  #pragma unroll
  for (int i = 0; i < 5; ++i) {
    const unsigned* rot = (i & 1) ? rotB : rotA;
    #pragma unroll
    for (int r = 0; r < 4; ++r) {
      x0 += x1;
      x1 = (x1 << rot[r]) | (x1 >> (32u - rot[r]));
      x1 ^= x0;
    }
    x0 += ks[(i + 1) % 3];
    x1 += ks[(i + 2) % 3] + (unsigned)(i + 1);
  }
  o0 = x0; o1 = x1;
}

DEVI float erfinv_xla(float x) {
  float w = -log1pf(-x * x);
  float p;
  if (w < 5.f) {
    w -= 2.5f;
    p = 2.81022636e-08f;
    p = fmaf(p, w, 3.43273939e-07f);
    p = fmaf(p, w, -3.5233877e-06f);
    p = fmaf(p, w, -4.39150654e-06f);
    p = fmaf(p, w, 0.00021858087f);
    p = fmaf(p, w, -0.00125372503f);
    p = fmaf(p, w, -0.00417768164f);
    p = fmaf(p, w, 0.246640727f);
    p = fmaf(p, w, 1.50140941f);
  } else {
    w = sqrtf(w) - 3.f;
    p = -0.000200214257f;
    p = fmaf(p, w, 0.000100950558f);
    p = fmaf(p, w, 0.00134934322f);
    p = fmaf(p, w, -0.00367342844f);
    p = fmaf(p, w, 0.00573950773f);
    p = fmaf(p, w, -0.0076224613f);
    p = fmaf(p, w, 0.00943887047f);
    p = fmaf(p, w, 1.00167406f);
    p = fmaf(p, w, 2.83297682f);
  }
  return p * x;
}

DEVI float normal_from_bits(unsigned bits) {
  unsigned fb = (bits >> 9) | 0x3F800000u;
  float f = __uint_as_float(fb) - 1.0f;
  const float lo = -0.99999994f;
  float u = f * (1.0f - lo) + lo;
  u = fmaxf(lo, u);
  return 1.41421356237f * erfinv_xla(u);
}

DEVI unsigned f2o(float f) { unsigned u = __float_as_uint(f); return (u & 0x80000000u) ? ~u : (u | 0x80000000u); }
DEVI float o2f(unsigned u) { return (u & 0x80000000u) ? __uint_as_float(u & 0x7FFFFFFFu) : __uint_as_float(~u); }

DEVI unsigned short f2bf(float x) {  // RNE f32 -> bf16
  unsigned u = __float_as_uint(x);
  return (unsigned short)((u + 0x7FFFu + ((u >> 16) & 1u)) >> 16);
}
DEVI float bf2f(unsigned short h) { return __uint_as_float((unsigned)h << 16); }

DEVI void blockMinMax(float lmn, float lmx, float* smem, unsigned* slot) {
  float* smn = smem; float* smx = smem + 256;
  int t = threadIdx.x;
  smn[t] = lmn; smx[t] = lmx;
  __syncthreads();
  for (int s = 128; s > 0; s >>= 1) {
    if (t < s) { smn[t] = fminf(smn[t], smn[t + s]); smx[t] = fmaxf(smx[t], smx[t + s]); }
    __syncthreads();
  }
  if (t == 0) { atomicMin(slot + 0, f2o(smn[0])); atomicMax(slot + 1, f2o(smx[0])); }
}

DEVI s8v expand_bits(unsigned b) {
  s8v f;
  #pragma unroll
  for (int j = 0; j < 8; ++j) f[j] = (short)(((b >> j) & 1u) ? 0x3F80 : 0);
  return f;
}

// ---------------- kernels ----------------
__global__ __launch_bounds__(256) void k_init(float* __restrict__ z1, float* __restrict__ z2,
                                              float* __restrict__ tsum, unsigned* __restrict__ slots) {
  int i = blockIdx.x * 256 + threadIdx.x;
  if (i < R2 * 512) z1[i] = 0.f;
  if (i < R2 * 128) z2[i] = 0.f;
  if (i < R2 * 64) tsum[i] = 0.f;
  if (i < 4) { slots[2 * i] = f2o(3.402823466e38f); slots[2 * i + 1] = f2o(-3.402823466e38f); }
}

// All 4 expanded noisy-weight matrices, fragment-major layout:
// B[(((n>>4)*KG + (pk>>2))*2 + h)*512 + ((pk&3)*16 + (n&15))*8 + bit], KG = K/4, h=0:hi,1:lo
__global__ __launch_bounds__(256) void k_gen_all(
    const float* __restrict__ W2A, const float* __restrict__ W2B,
    const float* __restrict__ W3A, const float* __restrict__ W3B,
    short* __restrict__ B2A, short* __restrict__ B2B,
    short* __restrict__ B3A, short* __restrict__ B3B,
    float* __restrict__ W72A, float* __restrict__ W72B,
    float* __restrict__ W73A, float* __restrict__ W73B) {
  int t = blockIdx.x * 256 + threadIdx.x;
  const float* W; short* Bf; float* W7; int N, K; unsigned layer; int perm = 0;
  int lt = t;
  if (lt < 524288) { W = W2A; Bf = B2A; W7 = W72A; N = 512; K = 128; layer = 0u; }
  else if ((lt -= 524288) < 524288) { W = W2B; Bf = B2B; W7 = W72B; N = 128; K = 512; layer = 1u; }
  else if ((lt -= 524288) < 1638400) { W = W3A; Bf = B3A; W7 = W73A; N = 640; K = 320; layer = 2u; perm = 1; }
  else if ((lt -= 1638400) < 655360) { W = W3B; Bf = B3B; W7 = W73B; N = 128; K = 640; layer = 3u; }
  else return;
  int n_elem = N * K;
  int bit = lt / n_elem;
  int e = lt - bit * n_elem;
  unsigned kl0, kl1, kb0, kb1, r0, r1;
  tf2x32(0u, 42u, 0u, layer, kl0, kl1);
  tf2x32(kl0, kl1, 0u, (unsigned)bit, kb0, kb1);
  tf2x32(kb0, kb1, 0u, (unsigned)e, r0, r1);
  float w = W[e];
  float wn = w + normal_from_bits(r0 ^ r1) * fabsf(w) * 0.1f;
  float sv = ldexpf(wn, bit);
  unsigned short hi = f2bf(sv);
  unsigned short lo = f2bf(sv - bf2f(hi));
  int n = e / K, k = e - n * K;
  int pk = k;
  if (perm) {
    if (k >= 128 && k < 192) pk = k + 64;        // node_k -> 192..256
    else if (k >= 192 && k < 256) pk = k - 64;   // edge_ij -> 128..192
  }
  int KG = K >> 2;
  size_t off = (((size_t)(n >> 4) * KG + (pk >> 2)) * 2) * 512
             + (size_t)(((pk & 3) << 4) + (n & 15)) * 8 + bit;
  Bf[off] = (short)hi;
  Bf[off + 512] = (short)lo;
  if (bit == 7) W7[e] = wn;
}

__global__ __launch_bounds__(256) void k_rowsum_all(
    const float* __restrict__ W72A, const float* __restrict__ W72B,
    const float* __restrict__ W73A, const float* __restrict__ W73B,
    float* __restrict__ rs) {  // rs = RS2A base; RS2B/RS3A/RS3B contiguous after
  int o = blockIdx.x * 256 + threadIdx.x;
  const float* p; int cols; float* dst; int lo;
  if (o < 512) { p = W72A; cols = 128; dst = rs; lo = o; }
  else if (o < 640) { p = W72B; cols = 512; dst = rs + 512; lo = o - 512; }
  else if (o < 1280) { p = W73A; cols = 320; dst = rs + 640; lo = o - 640; }
  else if (o < 1408) { p = W73B; cols = 640; dst = rs + 1280; lo = o - 1280; }
  else return;
  const float* row = p + (size_t)lo * cols;
  float s = 0.f;
  for (int j = 0; j < cols; ++j) s += row[j];
  dst[lo] = s;
}

// fused c2in build (+slot0 minmax) and NK gather
__global__ __launch_bounds__(256) void k_build(const float* __restrict__ node, const float* __restrict__ mask,
                                               const int* __restrict__ nidx, float* __restrict__ c2in,
                                               float* __restrict__ NK, unsigned* __restrict__ slot) {
  __shared__ float sred[512];
  int idx = blockIdx.x * 256 + threadIdx.x;
  float lmn = 3.4e38f, lmx = -3.4e38f;
  if (idx < R2 * 128) {
    int row = idx >> 7, c = idx & 127;
    float v;
    if (c < 64) v = node[(size_t)(row / 20) * 64 + c];
    else {
      int b = row / 960;
      v = node[(size_t)(b * 48 + nidx[row]) * 64 + (c - 64)] * mask[row];
    }
    c2in[idx] = v; lmn = v; lmx = v;
  } else if (idx < R2 * 192) {
    int i2 = idx - R2 * 128;
    int row = i2 >> 6, c = i2 & 63;
    int b = row / 960;
    NK[i2] = node[(size_t)(b * 48 + nidx[row]) * 64 + c];
  }
  blockMinMax(lmn, lmx, sred, slot);
}

// fused min/max for all 4 pieces of the materialized c3 (slot 4)
__global__ __launch_bounds__(256) void k_minmax4(const float* __restrict__ node, const float* __restrict__ edge,
                                                 const float* __restrict__ c2in, const float* __restrict__ NK,
                                                 const int* __restrict__ nidx, unsigned* __restrict__ slot) {
  __shared__ float sred[512];
  const int n0 = 12288, n1 = n0 + 245760, n2 = n1 + 245760, total = n2 + 4915200;
  float lmn = 3.4e38f, lmx = -3.4e38f;
  for (int idx = blockIdx.x * 256 + threadIdx.x; idx < total; idx += gridDim.x * 256) {
    float v, v2;
    if (idx < n0) { v = node[idx]; v2 = v; }
    else if (idx < n1) { v = edge[idx - n0]; v2 = v; }
    else if (idx < n2) {
      int j = idx - n1; int r = j >> 6, c = j & 63;
      v = c2in[(size_t)r * 128 + 64 + c]; v2 = v;
    } else {
      int j = idx - n2; int bij = j / 1280, t = j - bij * 1280;
      int b = bij / 960;
      size_t base = (size_t)((b * 48 + nidx[bij]) * 20) * 64 + t;
      v = NK[base]; v2 = edge[base];
    }
    lmn = fminf(lmn, fminf(v, v2)); lmx = fmaxf(lmx, fmaxf(v, v2));
  }
  blockMinMax(lmn, lmx, sred, slot);
}

__global__ __launch_bounds__(256) void k_quant(const float* __restrict__ X, int ld, int col0,
                                               int rows, int cols, const unsigned* __restrict__ slot,
                                               unsigned char* __restrict__ Q, int qld, int qc0) {
  int idx = blockIdx.x * 256 + threadIdx.x;
  if (idx >= rows * cols) return;
  int r = idx / cols, c = idx - r * cols;
  const float mn = o2f(slot[0]), mx = o2f(slot[1]);
  float invd = 255.f / (mx - mn);
  Q[(size_t)r * qld + qc0 + c] = (unsigned char)((X[(size_t)r * ld + col0 + c] - mn) * invd);
}

// fused quantization of all 3-body pieces (slot 4)
__global__ __launch_bounds__(256) void k_quant3(const float* __restrict__ node, const float* __restrict__ edge,
                                                const float* __restrict__ c2in, const float* __restrict__ NK,
                                                const unsigned* __restrict__ slot,
                                                unsigned char* __restrict__ QND, unsigned char* __restrict__ QP2,
                                                unsigned char* __restrict__ QP3) {
  int idx = blockIdx.x * 256 + threadIdx.x;
  const int n0 = 12288, seg = 245760;
  if (idx >= n0 + 4 * seg) return;
  const float mn = o2f(slot[0]), mx = o2f(slot[1]);
  const float invd = 255.f / (mx - mn);
  if (idx < n0) { QND[idx] = (unsigned char)((node[idx] - mn) * invd); return; }
  int j = idx - n0;
  int s = j / seg; int jj = j - s * seg;
  int r = jj >> 6, c = jj & 63;
  float v; unsigned char* dst;
  if (s == 0)      { v = c2in[(size_t)r * 128 + 64 + c]; dst = QP2 + (size_t)r * 128 + c; }
  else if (s == 1) { v = edge[(size_t)r * 64 + c];       dst = QP2 + (size_t)r * 128 + 64 + c; }
  else if (s == 2) { v = NK[(size_t)r * 64 + c];         dst = QP3 + (size_t)r * 128 + c; }
  else             { v = edge[(size_t)r * 64 + c];       dst = QP3 + (size_t)r * 128 + 64 + c; }
  *dst = (unsigned char)((v - mn) * invd);
}

// Generic MFMA bit-serial GEMM, fragment-major B; split-K via gridDim.z
// accflag: 0=store, 3=atomicAdd. block 128x128, 4 waves 2x2.
__global__ __launch_bounds__(256) void k_mfma_gemm(
    const unsigned char* __restrict__ Q, int ldq,
    const short* __restrict__ B, int KGfull, int kg0,
    int M, int Nfull, int KB, float* __restrict__ Z, int accflag) {
  const int tid = threadIdx.x;
  const int lane = tid & 63, wave = tid >> 6;
  const int wr = wave >> 1, wc = wave & 1;
  const int l15 = lane & 15, l4 = lane >> 4;
  const int mbase = blockIdx.y * 128 + wr * 64;
  const int nbase = blockIdx.x * 128 + wc * 64;
  const int kq0 = blockIdx.z * KB;
  f4v acc[4][4];
  #pragma unroll
  for (int a = 0; a < 4; ++a)
    #pragma unroll
    for (int b = 0; b < 4; ++b) acc[a][b] = f4v{0.f, 0.f, 0.f, 0.f};
  for (int ks = 0; ks < KB; ks += 4) {
    int kg = kg0 + ((kq0 + ks) >> 2);
    s8v af[4];
    #pragma unroll
    for (int mf = 0; mf < 4; ++mf) {
      int row = mbase + mf * 16 + l15; if (row >= M) row = M - 1;
      unsigned w = *(const unsigned*)(Q + (size_t)row * ldq + kq0 + ks);
      af[mf] = expand_bits((w >> (l4 * 8)) & 255u);
    }
    #pragma unroll
    for (int nf = 0; nf < 4; ++nf) {
      size_t o = (((size_t)(nbase / 16 + nf) * KGfull + kg) * 2) * 512 + (size_t)lane * 8;
      s8v bh = *(const s8v*)(B + o);
      s8v bl = *(const s8v*)(B + o + 512);
      #pragma unroll
      for (int mf = 0; mf < 4; ++mf) {
        acc[mf][nf] = __builtin_amdgcn_mfma_f32_16x16x32_bf16(af[mf], bh, acc[mf][nf], 0, 0, 0);
        acc[mf][nf] = __builtin_amdgcn_mfma_f32_16x16x32_bf16(af[mf], bl, acc[mf][nf], 0, 0, 0);
      }
    }
  }
  #pragma unroll
  for (int mf = 0; mf < 4; ++mf) {
    #pragma unroll
    for (int r = 0; r < 4; ++r) {
      int m = mbase + mf * 16 + l4 * 4 + r;
      if (m >= M) continue;
      float* zp = Z + (size_t)m * Nfull + nbase;
      #pragma unroll
      for (int nf = 0; nf < 4; ++nf) {
        int n = nf * 16 + l15;
        if (accflag == 0) zp[n] = acc[mf][nf][r];
        else atomicAdd(zp + n, acc[mf][nf][r]);
      }
    }
  }
}

// Merged P2/P3 GEMM (fragment-major B3A, KGfull=80); P2 half adds P1 row in epilogue
__global__ __launch_bounds__(256) void k_mfma_p23(
    const unsigned char* __restrict__ Q2, const unsigned char* __restrict__ Q3,
    const short* __restrict__ B,
    const float* __restrict__ P1, float* __restrict__ P2, float* __restrict__ P3) {
  const int half = blockIdx.y >= 30;
  const int by = blockIdx.y - half * 30;
  const unsigned char* Q = half ? Q3 : Q2;
  float* Z = half ? P3 : P2;
  const int kg0 = half ? 48 : 16;
  const int tid = threadIdx.x;
  const int lane = tid & 63, wave = tid >> 6;
  const int wr = wave >> 1, wc = wave & 1;
  const int l15 = lane & 15, l4 = lane >> 4;
  const int mbase = by * 128 + wr * 64;
  const int nbase = blockIdx.x * 128 + wc * 64;
  f4v acc[4][4];
  #pragma unroll
  for (int a = 0; a < 4; ++a)
    #pragma unroll
    for (int b = 0; b < 4; ++b) acc[a][b] = f4v{0.f, 0.f, 0.f, 0.f};
  for (int ks = 0; ks < 128; ks += 4) {
    int kg = kg0 + (ks >> 2);
    s8v af[4];
    #pragma unroll
    for (int mf = 0; mf < 4; ++mf) {
      unsigned w = *(const unsigned*)(Q + (size_t)(mbase + mf * 16 + l15) * 128 + ks);
      af[mf] = expand_bits((w >> (l4 * 8)) & 255u);
    }
    #pragma unroll
    for (int nf = 0; nf < 4; ++nf) {
      size_t o = (((size_t)(nbase / 16 + nf) * 80 + kg) * 2) * 512 + (size_t)lane * 8;
      s8v bh = *(const s8v*)(B + o);
      s8v bl = *(const s8v*)(B + o + 512);
      #pragma unroll
      for (int mf = 0; mf < 4; ++mf) {
        acc[mf][nf] = __builtin_amdgcn_mfma_f32_16x16x32_bf16(af[mf], bh, acc[mf][nf], 0, 0, 0);
        acc[mf][nf] = __builtin_amdgcn_mfma_f32_16x16x32_bf16(af[mf], bl, acc[mf][nf], 0, 0, 0);
      }
    }
  }
  #pragma unroll
  for (int mf = 0; mf < 4; ++mf) {
    #pragma unroll
    for (int r = 0; r < 4; ++r) {
      int m = mbase + mf * 16 + l4 * 4 + r;
      float* zp = Z + (size_t)m * 640 + nbase;
      const float* ap = P1 + (size_t)(m / 20) * 640 + nbase;
      #pragma unroll
      for (int nf = 0; nf < 4; ++nf) {
        int n = nf * 16 + l15;
        zp[n] = half ? acc[mf][nf][r] : (acc[mf][nf][r] + ap[n]);
      }
    }
  }
}

__global__ __launch_bounds__(256) void k_act1(const float* __restrict__ z1, const float* __restrict__ rs,
                                              const unsigned* __restrict__ slot0, float* __restrict__ c2b,
                                              unsigned* __restrict__ slot1) {
  __shared__ float sred[512];
  const float mn = o2f(slot0[0]), mx = o2f(slot0[1]);
  int idx = blockIdx.x * 256 + threadIdx.x;
  float lmn = 3.4e38f, lmx = -3.4e38f;
  if (idx < R2 * 512) {
    int o = idx & 511;
    float v = fmaxf(0.f, z1[idx] * (1.f / 255.f) * (mx - mn) + mn * rs[o]);
    c2b[idx] = v; lmn = v; lmx = v;
  }
  blockMinMax(lmn, lmx, sred, slot1);
}

__global__ __launch_bounds__(256) void k_act2(const float* __restrict__ z2, const float* __restrict__ rs,
                                              const unsigned* __restrict__ slot, float* __restrict__ two) {
  int idx = blockIdx.x * 256 + threadIdx.x;
  if (idx >= R2 * 64) return;
  const float mn = o2f(slot[0]), mx = o2f(slot[1]);
  int row = idx >> 6, c = idx & 63;
  float d = (mx - mn) * (1.f / 255.f);
  float g = z2[(size_t)row * 128 + c] * d + mn * rs[c];
  float e = z2[(size_t)row * 128 + 64 + c] * d + mn * rs[64 + c];
  two[idx] = (1.f / (1.f + expf(-g))) * tanhf(e);
}

// min/max of relu(requant(z3)) — block per (b,i,j)
__global__ __launch_bounds__(256) void k_minmax3(
    const float* __restrict__ P12, const float* __restrict__ P3,
    const float* __restrict__ rs3a, const int* __restrict__ nidx,
    const unsigned* __restrict__ slot2, unsigned* __restrict__ slot3) {
  __shared__ float p12s[640];
  __shared__ float bias[640];
  __shared__ float sred[512];
  const int bij = blockIdx.x;
  const int b = bij / 960;
  const int jp = nidx[bij];
  const size_t p3b = (size_t)((b * 48 + jp) * 20) * 640;
  const float mn2 = o2f(slot2[0]), mx2 = o2f(slot2[1]);
  const float sc2 = (mx2 - mn2) * (1.f / 255.f);
  for (int k = threadIdx.x; k < 640; k += 256) {
    p12s[k] = P12[(size_t)bij * 640 + k];
    bias[k] = mn2 * rs3a[k];
  }
  __syncthreads();
  float lmn = 3.4e38f, lmx = -3.4e38f;
  for (int t = threadIdx.x; t < 20 * 640; t += 256) {
    int knb = t / 640, k = t - knb * 640;
    float v = fmaxf(0.f, (p12s[k] + P3[p3b + t]) * sc2 + bias[k]);
    lmn = fminf(lmn, v); lmx = fmaxf(lmx, v);
  }
  blockMinMax(lmn, lmx, sred, slot3);
}

// Fused 3-body layer 2: 64-row blocks, fragment-major B (coalesced 1KB loads),
// register double-buffered B prefetch, epilogue sigmoid*tanh*mask + atomic k-sum.
__global__ __launch_bounds__(256) void k_mfma_l3b(
    const float* __restrict__ P12, const float* __restrict__ P3,
    const float* __restrict__ rs3a, const float* __restrict__ rs3b,
    const short* __restrict__ B,
    const int* __restrict__ nidx, const float* __restrict__ mask,
    const unsigned* __restrict__ slotA, const unsigned* __restrict__ slotB,
    float* __restrict__ tsum) {
  __shared__ unsigned char qt[64 * 648];
  const int tid = threadIdx.x;
  const int s0 = blockIdx.x * 64;
  const float mn2 = o2f(slotA[0]), mx2 = o2f(slotA[1]);
  const float mn3 = o2f(slotB[0]), mx3 = o2f(slotB[1]);
  const float sc2 = (mx2 - mn2) * (1.f / 255.f);
  const float invd3 = 255.f / (mx3 - mn3);
  {
    int r = tid >> 2, kq = (tid & 3) * 160;
    int s = s0 + r;
    int bij = s / 20, knb = s - bij * 20, b = bij / 960;
    int p3row = (b * 48 + nidx[bij]) * 20 + knb;
    const float* pa = P12 + (size_t)bij * 640;
    const float* pb = P3 + (size_t)p3row * 640;
    for (int k = kq; k < kq + 160; k += 4) {
      float4 va = *(const float4*)(pa + k);
      float4 vb = *(const float4*)(pb + k);
      float v0 = fmaxf(0.f, (va.x + vb.x) * sc2 + mn2 * rs3a[k + 0]);
      float v1 = fmaxf(0.f, (va.y + vb.y) * sc2 + mn2 * rs3a[k + 1]);
      float v2 = fmaxf(0.f, (va.z + vb.z) * sc2 + mn2 * rs3a[k + 2]);
      float v3 = fmaxf(0.f, (va.w + vb.w) * sc2 + mn2 * rs3a[k + 3]);
      unsigned pk = (unsigned)((v0 - mn3) * invd3) | ((unsigned)((v1 - mn3) * invd3) << 8)
                  | ((unsigned)((v2 - mn3) * invd3) << 16) | ((unsigned)((v3 - mn3) * invd3) << 24);
      *(unsigned*)(&qt[(size_t)r * 648 + k]) = pk;
    }
  }
  __syncthreads();
  const int lane = tid & 63, wave = tid >> 6;
  const int wm = wave >> 1, wn = wave & 1;
  const int l15 = lane & 15, l4 = lane >> 4;
  const int nfl[4] = {2 * wn, 2 * wn + 1, 2 * wn + 4, 2 * wn + 5};
  size_t bb[4];
  #pragma unroll
  for (int j = 0; j < 4; ++j) bb[j] = ((size_t)nfl[j] * 160 * 2) * 512 + (size_t)lane * 8;
  f4v acc[2][4];
  #pragma unroll
  for (int a = 0; a < 2; ++a)
    #pragma unroll
    for (int b = 0; b < 4; ++b) acc[a][b] = f4v{0.f, 0.f, 0.f, 0.f};
  s8v cbh[4], cbl[4];
  #pragma unroll
  for (int j = 0; j < 4; ++j) {
    cbh[j] = *(const s8v*)(B + bb[j]);
    cbl[j] = *(const s8v*)(B + bb[j] + 512);
  }
  const unsigned char* qrow = &qt[(size_t)(wm * 32 + l15) * 648];
  for (int kg = 0; kg < 160; ++kg) {
    int ks = kg * 4;
    unsigned w0 = *(const unsigned*)(qrow + ks);
    unsigned w1 = *(const unsigned*)(qrow + 16 * 648 + ks);
    s8v af0 = expand_bits((w0 >> (l4 * 8)) & 255u);
    s8v af1 = expand_bits((w1 >> (l4 * 8)) & 255u);
    s8v nbh[4], nbl[4];
    #pragma unroll
    for (int j = 0; j < 4; ++j) {     // prefetch next kg (last iter reads 2KB past B3B end: inside ws, unused)
      size_t o = bb[j] + (size_t)(kg + 1) * 1024;
      nbh[j] = *(const s8v*)(B + o);
      nbl[j] = *(const s8v*)(B + o + 512);
    }
    #pragma unroll
    for (int j = 0; j < 4; ++j) {
      acc[0][j] = __builtin_amdgcn_mfma_f32_16x16x32_bf16(af0, cbh[j], acc[0][j], 0, 0, 0);
      acc[0][j] = __builtin_amdgcn_mfma_f32_16x16x32_bf16(af0, cbl[j], acc[0][j], 0, 0, 0);
      acc[1][j] = __builtin_amdgcn_mfma_f32_16x16x32_bf16(af1, cbh[j], acc[1][j], 0, 0, 0);
      acc[1][j] = __builtin_amdgcn_mfma_f32_16x16x32_bf16(af1, cbl[j], acc[1][j], 0, 0, 0);
    }
    #pragma unroll
    for (int j = 0; j < 4; ++j) { cbh[j] = nbh[j]; cbl[j] = nbl[j]; }
  }
  const float d3 = (mx3 - mn3) * (1.f / 255.f);
  float rg[2], re[2];
  #pragma unroll
  for (int j = 0; j < 2; ++j) {
    int gcol = (2 * wn + j) * 16 + l15;
    rg[j] = mn3 * rs3b[gcol];
    re[j] = mn3 * rs3b[64 + gcol];
  }
  #pragma unroll
  for (int mf = 0; mf < 2; ++mf) {
    #pragma unroll
    for (int r = 0; r < 4; ++r) {
      int s = s0 + wm * 32 + mf * 16 + l4 * 4 + r;
      int bij = s / 20, knb = s - bij * 20, b = bij / 960;
      int p3row = (b * 48 + nidx[bij]) * 20 + knb;
      float mk = mask[p3row];
      #pragma unroll
      for (int j = 0; j < 2; ++j) {
        float g = acc[mf][j][r] * d3 + rg[j];
        float e = acc[mf][j + 2][r] * d3 + re[j];
        float val = (1.f / (1.f + expf(-g))) * tanhf(e) * mk;
        atomicAdd(&tsum[(size_t)bij * 64 + (2 * wn + j) * 16 + l15], val);
      }
    }
  }
}

__global__ __launch_bounds__(256) void k_bnstats2(const float* __restrict__ two, const float* __restrict__ tsum,
                                                  float* __restrict__ bn) {
  __shared__ float ss[512];
  const float* x = blockIdx.y ? tsum : two;
  float* mout = bn + (blockIdx.y ? 128 : 0);
  float* vout = mout + 64;
  int c = blockIdx.x, t = threadIdx.x;
  float s = 0.f, q = 0.f;
  for (int r = t; r < R2; r += 256) { float v = x[(size_t)r * 64 + c]; s += v; q += v * v; }
  ss[t] = s; ss[256 + t] = q;
  __syncthreads();
  for (int st = 128; st > 0; st >>= 1) {
    if (t < st) { ss[t] += ss[t + st]; ss[256 + t] += ss[256 + t + st]; }
    __syncthreads();
  }
  if (t == 0) { float m = ss[0] / (float)R2; mout[c] = m; vout[c] = ss[256] / (float)R2 - m * m; }
}

__global__ __launch_bounds__(256) void k_final(const float* __restrict__ edge, const float* __restrict__ two,
                                               const float* __restrict__ tsum, const float* __restrict__ bn,
                                               const float* __restrict__ g2, const float* __restrict__ b2,
                                               const float* __restrict__ g3, const float* __restrict__ b3,
                                               float* __restrict__ out) {
  int idx = blockIdx.x * 256 + threadIdx.x;
  if (idx >= R2 * 64) return;
  int c = idx & 63;
  float t2 = (two[idx] - bn[c]) / sqrtf(bn[64 + c] + 1e-5f) * g2[c] + b2[c];
  float t3 = (tsum[idx] - bn[128 + c]) / sqrtf(bn[192 + c] + 1e-5f) * g3[c] + b3[c];
  out[idx] = fmaxf(0.f, edge[idx] + t2 + t3);
}

// ---------------- host launcher ----------------
extern "C" void kernel_launch(void* const* d_in, const int* in_sizes, int n_in,
                              void* d_out, int out_size, void* d_ws, size_t ws_size,
                              hipStream_t stream) {
  (void)in_sizes; (void)n_in; (void)out_size; (void)ws_size;
  const float* node   = (const float*)d_in[0];
  const float* edge   = (const float*)d_in[1];
  const float* mask   = (const float*)d_in[2];
  const float* c_two  = (const float*)d_in[3];
  const float* c_two2 = (const float*)d_in[4];
  const float* c_three  = (const float*)d_in[5];
  const float* c_three2 = (const float*)d_in[6];
  const float* bn2g = (const float*)d_in[7];
  const float* bn2b = (const float*)d_in[8];
  const float* bn3g = (const float*)d_in[9];
  const float* bn3b = (const float*)d_in[10];
  const int*   nidx = (const int*)d_in[11];
  float* ws = (float*)d_ws;
  unsigned* slots = (unsigned*)(ws + OFF_SLOT);
  float* out = (float*)d_out;
  short* B2A = (short*)(ws + OFF_B2A);
  short* B2B = (short*)(ws + OFF_B2B);
  short* B3A = (short*)(ws + OFF_B3A);
  short* B3B = (short*)(ws + OFF_B3B);
  unsigned char* Q2A = (unsigned char*)(ws + OFF_Q2A);
  unsigned char* Q2B = (unsigned char*)(ws + OFF_Q2B);
  unsigned char* QND = (unsigned char*)(ws + OFF_QND);
  unsigned char* QP2 = (unsigned char*)(ws + OFF_QP2);
  unsigned char* QP3 = (unsigned char*)(ws + OFF_QP3);

  k_init<<<7680, 256, 0, stream>>>(ws + OFF_Z1, ws + OFF_Z2, ws + OFF_TSUM, slots);

  k_gen_all<<<13056, 256, 0, stream>>>(c_two, c_two2, c_three, c_three2,
                                       B2A, B2B, B3A, B3B,
                                       ws + OFF_W72A, ws + OFF_W72B, ws + OFF_W73A, ws + OFF_W73B);
  k_rowsum_all<<<6, 256, 0, stream>>>(ws + OFF_W72A, ws + OFF_W72B, ws + OFF_W73A, ws + OFF_W73B,
                                      ws + OFF_RS2A);

  // two-body
  k_build<<<2880, 256, 0, stream>>>(node, mask, nidx, ws + OFF_C2IN, ws + OFF_NK, slots + 0);
  k_quant<<<1920, 256, 0, stream>>>(ws + OFF_C2IN, 128, 0, 3840, 128, slots + 0, Q2A, 128, 0);
  k_mfma_gemm<<<dim3(4, 30, 4), 256, 0, stream>>>(Q2A, 128, B2A, 32, 0, 3840, 512, 32, ws + OFF_Z1, 3);
  k_act1<<<7680, 256, 0, stream>>>(ws + OFF_Z1, ws + OFF_RS2A, slots + 0, ws + OFF_C2B, slots + 2);
  k_quant<<<7680, 256, 0, stream>>>(ws + OFF_C2B, 512, 0, 3840, 512, slots + 2, Q2B, 512, 0);
  k_mfma_gemm<<<dim3(1, 30, 8), 256, 0, stream>>>(Q2B, 512, B2B, 128, 0, 3840, 128, 64, ws + OFF_Z2, 3);
  k_act2<<<960, 256, 0, stream>>>(ws + OFF_Z2, ws + OFF_RS2B, slots + 2, ws + OFF_TWO);

  // three-body: piecewise c3 min/max + piece quantization
  k_minmax4<<<2048, 256, 0, stream>>>(node, edge, ws + OFF_C2IN, ws + OFF_NK, nidx, slots + 4);
  k_quant3<<<3888, 256, 0, stream>>>(node, edge, ws + OFF_C2IN, ws + OFF_NK, slots + 4, QND, QP2, QP3);

  // P1 (node_i), then merged P2/P3 (P1 folded into P2)
  k_mfma_gemm<<<dim3(5, 2, 1), 256, 0, stream>>>(QND, 64, B3A, 80, 0, 192, 640, 64, ws + OFF_P1, 0);
  k_mfma_p23<<<dim3(5, 60), 256, 0, stream>>>(QP2, QP3, B3A, ws + OFF_P1, ws + OFF_P2, ws + OFF_P3);

  k_minmax3<<<3840, 256, 0, stream>>>(ws + OFF_P2, ws + OFF_P3, ws + OFF_RS3A, nidx, slots + 4, slots + 6);
  k_mfma_l3b<<<1200, 256, 0, stream>>>(ws + OFF_P2, ws + OFF_P3, ws + OFF_RS3A, ws + OFF_RS3B,
                                       B3B, nidx, mask, slots + 4, slots + 6, ws + OFF_TSUM);

  k_bnstats2<<<dim3(64, 2), 256, 0, stream>>>(ws + OFF_TWO, ws + OFF_TSUM, ws + OFF_BN);
  k_final<<<960, 256, 0, stream>>>(edge, ws + OFF_TWO, ws + OFF_TSUM, ws + OFF_BN,
                                   bn2g, bn2b, bn3g, bn3b, out);
}